// Round 1
// baseline (6624.595 us; speedup 1.0000x reference)
//
#include <hip/hip_runtime.h>
#include <hip/hip_bf16.h>
#include <math.h>

// Problem constants (SentenceLSTM)
static constexpr int BB = 256;    // batch
static constexpr int NR = 196;    // regions
static constexpr int DV = 1024;   // vis embed dim
static constexpr int HH = 1024;   // hidden
static constexpr int AT = 256;    // att dim
static constexpr int SI = 1024;   // sem input dim (ctx)
static constexpr int WI = 1024;   // topic width
static constexpr int IS = 256;    // stop inner dim
static constexpr int ST = 10;     // sentence steps

__device__ __forceinline__ float sigmoidf_(float x) { return 1.0f / (1.0f + expf(-x)); }

// ---------------------------------------------------------------------------
// Generic fp32 GEMM:  C = act( A1 * W1^T + b1  [+ A2 * W2^T + b2] )
// A: [M,K] row-major.  W: [N,K] row-major.  C: [M,N] with leading dim ldc.
// 64x64 tile, 256 threads, 4x4 micro-tile per thread, k-major LDS (+pad).
// ACT: 0=none, 1=tanh.  DUAL: add second GEMM (same K).
// ---------------------------------------------------------------------------
template <int ACT, int DUAL>
__global__ __launch_bounds__(256) void gemm_nt(
    const float* __restrict__ A1, const float* __restrict__ W1, const float* __restrict__ b1,
    const float* __restrict__ A2, const float* __restrict__ W2, const float* __restrict__ b2,
    float* __restrict__ C, int M, int N, int K, int ldc)
{
    __shared__ __align__(16) float As[16][68];
    __shared__ __align__(16) float Ws[16][68];

    const int t  = threadIdx.x;
    const int tc = t & 15;        // micro-tile col group
    const int tr = t >> 4;        // micro-tile row group (0..15)
    const int n0 = blockIdx.x * 64;
    const int m0 = blockIdx.y * 64;

    const int lc = t & 15;        // k within chunk for loads
    const int lr = t >> 4;        // row base for loads (0..15)

    float acc[4][4] = {};

    const int npass = DUAL ? 2 : 1;
    for (int pass = 0; pass < npass; ++pass) {
        const float* __restrict__ A = (DUAL && pass) ? A2 : A1;
        const float* __restrict__ W = (DUAL && pass) ? W2 : W1;
        for (int k0 = 0; k0 < K; k0 += 16) {
            __syncthreads();
#pragma unroll
            for (int j = 0; j < 4; ++j) {
                const int r = lr + 16 * j;
                As[lc][r] = A[(size_t)(m0 + r) * K + k0 + lc];
                Ws[lc][r] = W[(size_t)(n0 + r) * K + k0 + lc];
            }
            __syncthreads();
#pragma unroll
            for (int kk = 0; kk < 16; ++kk) {
                const float4 af = *(const float4*)&As[kk][tr * 4];
                const float4 wf = *(const float4*)&Ws[kk][tc * 4];
                const float ar[4] = { af.x, af.y, af.z, af.w };
                const float wr[4] = { wf.x, wf.y, wf.z, wf.w };
#pragma unroll
                for (int i = 0; i < 4; ++i)
#pragma unroll
                    for (int j = 0; j < 4; ++j)
                        acc[i][j] = fmaf(ar[i], wr[j], acc[i][j]);
            }
        }
    }

#pragma unroll
    for (int i = 0; i < 4; ++i) {
        const int m = m0 + tr * 4 + i;
#pragma unroll
        for (int j = 0; j < 4; ++j) {
            const int n = n0 + tc * 4 + j;
            float v = acc[i][j] + b1[n];
            if (DUAL) v += b2[n];
            if (ACT == 1) v = tanhf(v);
            C[(size_t)m * ldc + n] = v;
        }
    }
}

// ---------------------------------------------------------------------------
// Attention logits + softmax.  One block per batch element.
// logits[n] = sum_a tanh(vis_att[b,n,a] + dec[b,a]) * fw[a] + fb
// scores[b,n] = softmax_n(logits)
// ---------------------------------------------------------------------------
__global__ __launch_bounds__(256) void att_softmax(
    const float* __restrict__ vis_att, const float* __restrict__ dec,
    const float* __restrict__ fw, const float* __restrict__ fbp,
    float* __restrict__ scores)
{
    const int b = blockIdx.x;
    const int t = threadIdx.x;
    const int lane = t & 63;
    const int w = t >> 6;

    __shared__ float decs[AT];
    __shared__ float logit[NR];
    __shared__ float red[16];

    decs[t] = dec[b * AT + t];
    __syncthreads();
    const float fb = fbp[0];

    // each wave owns rows n = w, w+4, ...
    for (int n = w; n < NR; n += 4) {
        const float* va = vis_att + ((size_t)b * NR + n) * AT;
        float s = 0.f;
#pragma unroll
        for (int ac = 0; ac < 4; ++ac) {
            const int a = ac * 64 + lane;
            s += tanhf(va[a] + decs[a]) * fw[a];
        }
        for (int off = 32; off; off >>= 1) s += __shfl_down(s, off);
        if (lane == 0) logit[n] = s + fb;
    }
    __syncthreads();

    // softmax over NR
    float m = -1e30f;
    if (t < NR) m = logit[t];
    for (int off = 32; off; off >>= 1) m = fmaxf(m, __shfl_down(m, off));
    if (lane == 0) red[w] = m;
    __syncthreads();
    m = fmaxf(fmaxf(red[0], red[1]), fmaxf(red[2], red[3]));

    float e = 0.f;
    if (t < NR) e = expf(logit[t] - m);
    float ssum = e;
    for (int off = 32; off; off >>= 1) ssum += __shfl_down(ssum, off);
    if (lane == 0) red[8 + w] = ssum;
    __syncthreads();
    const float S = red[8] + red[9] + red[10] + red[11];
    if (t < NR) scores[b * NR + t] = e / S;
}

// ---------------------------------------------------------------------------
// att_out[b,d] = sum_n scores[b,n] * vis[b,n,d]
// grid (DV/256, BB), 256 threads
// ---------------------------------------------------------------------------
__global__ __launch_bounds__(256) void att_apply(
    const float* __restrict__ scores, const float* __restrict__ vis,
    float* __restrict__ att_out)
{
    const int b = blockIdx.y;
    const int d = blockIdx.x * 256 + threadIdx.x;

    __shared__ float sc[NR];
    for (int n = threadIdx.x; n < NR; n += 256) sc[n] = scores[b * NR + n];
    __syncthreads();

    const float* vb = vis + (size_t)b * NR * DV + d;
    float acc = 0.f;
#pragma unroll 4
    for (int n = 0; n < NR; ++n) acc = fmaf(sc[n], vb[(size_t)n * DV], acc);
    att_out[b * DV + d] = acc;
}

// ---------------------------------------------------------------------------
// LSTM pointwise: gates [B,4H] (i,f,g,o), c updated in place, h_new written.
// ---------------------------------------------------------------------------
__global__ __launch_bounds__(256) void lstm_pw(
    const float* __restrict__ gates, float* __restrict__ c, float* __restrict__ hnew)
{
    const int idx = blockIdx.x * 256 + threadIdx.x;   // 0 .. B*HH-1
    const int b = idx >> 10;
    const int hh = idx & 1023;
    const float* g = gates + (size_t)b * 4 * HH;
    const float i = sigmoidf_(g[hh]);
    const float f = sigmoidf_(g[HH + hh]);
    const float gg = tanhf(g[2 * HH + hh]);
    const float o = sigmoidf_(g[3 * HH + hh]);
    const float cn = f * c[idx] + i * gg;
    c[idx] = cn;
    hnew[idx] = o * tanhf(cn);
}

// ---------------------------------------------------------------------------
// final stop projection: p[b,:] = pt[b,:] @ fw^T + fb   (fw: [2, IS])
// outp points at ps[:, s, :]; row stride ST*2.
// ---------------------------------------------------------------------------
__global__ __launch_bounds__(256) void stop_final(
    const float* __restrict__ pt, const float* __restrict__ fw,
    const float* __restrict__ fb, float* __restrict__ outp)
{
    const int b = blockIdx.x;
    const int t = threadIdx.x;
    const int lane = t & 63;
    const int w = t >> 6;

    __shared__ float red[16];
    const float v = pt[b * IS + t];
    float p0 = v * fw[t];
    float p1 = v * fw[IS + t];
    for (int off = 32; off; off >>= 1) {
        p0 += __shfl_down(p0, off);
        p1 += __shfl_down(p1, off);
    }
    if (lane == 0) { red[w] = p0; red[8 + w] = p1; }
    __syncthreads();
    if (t == 0) {
        outp[(size_t)b * ST * 2 + 0] = red[0] + red[1] + red[2] + red[3] + fb[0];
        outp[(size_t)b * ST * 2 + 1] = red[8] + red[9] + red[10] + red[11] + fb[1];
    }
}

// ---------------------------------------------------------------------------
extern "C" void kernel_launch(void* const* d_in, const int* in_sizes, int n_in,
                              void* d_out, int out_size, void* d_ws, size_t ws_size,
                              hipStream_t stream)
{
    const float* vis        = (const float*)d_in[0];
    // d_in[1]: sentences (int64) — only its shape matters (S=10), unused here.
    const float* enc_att_w  = (const float*)d_in[2];
    const float* enc_att_b  = (const float*)d_in[3];
    const float* dec_att_w  = (const float*)d_in[4];
    const float* dec_att_b  = (const float*)d_in[5];
    const float* full_att_w = (const float*)d_in[6];
    const float* full_att_b = (const float*)d_in[7];
    const float* ctx_w      = (const float*)d_in[8];
    const float* ctx_b      = (const float*)d_in[9];
    const float* W_ih       = (const float*)d_in[10];
    const float* b_ih       = (const float*)d_in[11];
    const float* W_hh       = (const float*)d_in[12];
    const float* b_hh       = (const float*)d_in[13];
    const float* topic_hid_w = (const float*)d_in[14];
    const float* topic_hid_b = (const float*)d_in[15];
    const float* topic_ctx_w = (const float*)d_in[16];
    const float* topic_ctx_b = (const float*)d_in[17];
    const float* stop_prev_w = (const float*)d_in[18];
    const float* stop_prev_b = (const float*)d_in[19];
    const float* stop_cur_w  = (const float*)d_in[20];
    const float* stop_cur_b  = (const float*)d_in[21];
    const float* final_stop_w = (const float*)d_in[22];
    const float* final_stop_b = (const float*)d_in[23];

    float* out_topics = (float*)d_out;                       // [B, ST, WI]
    float* out_ps     = (float*)d_out + (size_t)BB * ST * WI; // [B, ST, 2]

    // workspace carve-up
    char* ws = (char*)d_ws;
    size_t off = 0;
    auto alloc = [&](size_t bytes) -> float* {
        float* p = (float*)(ws + off);
        off += (bytes + 255) & ~(size_t)255;
        return p;
    };
    float* vis_att = alloc((size_t)BB * NR * AT * 4);  // 51.4 MB
    float* hA      = alloc((size_t)BB * HH * 4);
    float* hB      = alloc((size_t)BB * HH * 4);
    float* cbuf    = alloc((size_t)BB * HH * 4);
    float* dec     = alloc((size_t)BB * AT * 4);
    float* scores  = alloc((size_t)BB * NR * 4);
    float* att_out = alloc((size_t)BB * DV * 4);
    float* ctx     = alloc((size_t)BB * SI * 4);
    float* gates   = alloc((size_t)BB * 4 * HH * 4);
    float* pt      = alloc((size_t)BB * IS * 4);
    if (off > ws_size) return;  // workspace too small — fail visibly

    hipMemsetAsync(hA, 0, (size_t)BB * HH * 4, stream);
    hipMemsetAsync(cbuf, 0, (size_t)BB * HH * 4, stream);

    // hoisted encoder projection: vis_att = vis @ enc_att_w^T + enc_att_b
    gemm_nt<0, 0><<<dim3(AT / 64, (BB * NR) / 64), 256, 0, stream>>>(
        vis, enc_att_w, enc_att_b, nullptr, nullptr, nullptr,
        vis_att, BB * NR, AT, DV, AT);

    float* hc = hA;  // h_prev
    float* hn = hB;  // h_new
    for (int s = 0; s < ST; ++s) {
        // dec = h @ dec_att_w^T + dec_att_b
        gemm_nt<0, 0><<<dim3(AT / 64, BB / 64), 256, 0, stream>>>(
            hc, dec_att_w, dec_att_b, nullptr, nullptr, nullptr,
            dec, BB, AT, HH, AT);
        // scores = softmax(tanh(vis_att + dec) . fw + fb)
        att_softmax<<<BB, 256, 0, stream>>>(vis_att, dec, full_att_w, full_att_b, scores);
        // att_out = scores . vis
        att_apply<<<dim3(DV / 256, BB), 256, 0, stream>>>(scores, vis, att_out);
        // ctx = att_out @ ctx_w^T + ctx_b
        gemm_nt<0, 0><<<dim3(SI / 64, BB / 64), 256, 0, stream>>>(
            att_out, ctx_w, ctx_b, nullptr, nullptr, nullptr,
            ctx, BB, SI, DV, SI);
        // gates = ctx @ W_ih^T + b_ih + h @ W_hh^T + b_hh
        gemm_nt<0, 1><<<dim3(4 * HH / 64, BB / 64), 256, 0, stream>>>(
            ctx, W_ih, b_ih, hc, W_hh, b_hh,
            gates, BB, 4 * HH, SI, 4 * HH);
        // LSTM pointwise -> c (in place), hn
        lstm_pw<<<(BB * HH) / 256, 256, 0, stream>>>(gates, cbuf, hn);
        // topic = tanh(hn @ topic_hid_w^T + b + ctx @ topic_ctx_w^T + b) -> out
        gemm_nt<1, 1><<<dim3(WI / 64, BB / 64), 256, 0, stream>>>(
            hn, topic_hid_w, topic_hid_b, ctx, topic_ctx_w, topic_ctx_b,
            out_topics + (size_t)s * WI, BB, WI, HH, ST * WI);
        // pt = tanh(h_prev @ stop_prev_w^T + b + hn @ stop_cur_w^T + b)
        gemm_nt<1, 1><<<dim3(IS / 64, BB / 64), 256, 0, stream>>>(
            hc, stop_prev_w, stop_prev_b, hn, stop_cur_w, stop_cur_b,
            pt, BB, IS, HH, IS);
        // p = pt @ final_stop_w^T + final_stop_b -> out
        stop_final<<<BB, 256, 0, stream>>>(pt, final_stop_w, final_stop_b,
                                           out_ps + (size_t)s * 2);
        // swap h buffers
        float* tmp = hc; hc = hn; hn = tmp;
    }
}

// Round 2
// 4900.985 us; speedup vs baseline: 1.3517x; 1.3517x over previous
//
#include <hip/hip_runtime.h>
#include <hip/hip_bf16.h>
#include <math.h>

// Problem constants (SentenceLSTM)
static constexpr int BB = 256;    // batch
static constexpr int NR = 196;    // regions
static constexpr int DV = 1024;   // vis embed dim
static constexpr int HH = 1024;   // hidden
static constexpr int AT = 256;    // att dim
static constexpr int SI = 1024;   // sem input dim (ctx)
static constexpr int WI = 1024;   // topic width
static constexpr int IS = 256;    // stop inner dim
static constexpr int ST = 10;     // sentence steps

__device__ __forceinline__ float sigmoidf_(float x) { return 1.0f / (1.0f + expf(-x)); }

// ---------------------------------------------------------------------------
// gemm32: C = act( A1*W1^T + b1 [+ A2*W2^T + b2] )
// A: [M,K] rm, W: [N,K] rm. Tile 64Mx32N, micro 4x2, BK=32, 256 threads,
// register double-buffered global->LDS staging.
// ---------------------------------------------------------------------------
template <int ACT, int DUAL>
__global__ __launch_bounds__(256) void gemm32(
    const float* __restrict__ A1, const float* __restrict__ W1, const float* __restrict__ b1,
    const float* __restrict__ A2, const float* __restrict__ W2, const float* __restrict__ b2,
    float* __restrict__ C, int M, int N, int K, int ldc)
{
    __shared__ __align__(16) float As[32][68];
    __shared__ __align__(16) float Ws[32][36];

    const int t  = threadIdx.x;
    const int m0 = blockIdx.y * 64;
    const int n0 = blockIdx.x * 32;
    const int tr = t >> 4;              // 0..15 -> rows tr*4..+3
    const int tc = t & 15;              // 0..15 -> cols tc*2..+1
    const int ar = t >> 3;              // 0..31 (A rows ar, ar+32)
    const int kq = (t & 7) * 4;         // k offset within chunk

    const int KC  = K >> 5;             // chunks per pass
    const int nch = (DUAL ? 2 : 1) * KC;

    float4 aA0, aA1, aW0;
    {
        aA0 = *(const float4*)&A1[(size_t)(m0 + ar) * K + kq];
        aA1 = *(const float4*)&A1[(size_t)(m0 + ar + 32) * K + kq];
        aW0 = *(const float4*)&W1[(size_t)(n0 + ar) * K + kq];
    }

    float acc[4][2] = {};

    for (int c = 0; c < nch; ++c) {
        __syncthreads();
        As[kq + 0][ar] = aA0.x; As[kq + 1][ar] = aA0.y;
        As[kq + 2][ar] = aA0.z; As[kq + 3][ar] = aA0.w;
        As[kq + 0][ar + 32] = aA1.x; As[kq + 1][ar + 32] = aA1.y;
        As[kq + 2][ar + 32] = aA1.z; As[kq + 3][ar + 32] = aA1.w;
        Ws[kq + 0][ar] = aW0.x; Ws[kq + 1][ar] = aW0.y;
        Ws[kq + 2][ar] = aW0.z; Ws[kq + 3][ar] = aW0.w;
        __syncthreads();
        if (c + 1 < nch) {
            const int cn   = c + 1;
            const int pass = DUAL ? (cn >= KC ? 1 : 0) : 0;
            const int k0   = (cn - pass * KC) << 5;
            const float* __restrict__ A = pass ? A2 : A1;
            const float* __restrict__ W = pass ? W2 : W1;
            aA0 = *(const float4*)&A[(size_t)(m0 + ar) * K + k0 + kq];
            aA1 = *(const float4*)&A[(size_t)(m0 + ar + 32) * K + k0 + kq];
            aW0 = *(const float4*)&W[(size_t)(n0 + ar) * K + k0 + kq];
        }
#pragma unroll
        for (int kk = 0; kk < 32; ++kk) {
            const float4 af = *(const float4*)&As[kk][tr * 4];
            const float2 wf = *(const float2*)&Ws[kk][tc * 2];
            acc[0][0] = fmaf(af.x, wf.x, acc[0][0]); acc[0][1] = fmaf(af.x, wf.y, acc[0][1]);
            acc[1][0] = fmaf(af.y, wf.x, acc[1][0]); acc[1][1] = fmaf(af.y, wf.y, acc[1][1]);
            acc[2][0] = fmaf(af.z, wf.x, acc[2][0]); acc[2][1] = fmaf(af.z, wf.y, acc[2][1]);
            acc[3][0] = fmaf(af.w, wf.x, acc[3][0]); acc[3][1] = fmaf(af.w, wf.y, acc[3][1]);
        }
    }

#pragma unroll
    for (int i = 0; i < 4; ++i) {
        const int m = m0 + tr * 4 + i;
#pragma unroll
        for (int j = 0; j < 2; ++j) {
            const int n = n0 + tc * 2 + j;
            float v = acc[i][j] + b1[n];
            if (DUAL) v += b2[n];
            if (ACT) v = tanhf(v);
            C[(size_t)m * ldc + n] = v;
        }
    }
}

// ---------------------------------------------------------------------------
// gemm_big: vis_att = vis @ enc_att_w^T + b.  M=BB*NR, N=AT=256, K=DV.
// Tile 128x128, micro 8x8, BK=16, 256 threads, prefetched. grid (2, 392):
// N-blocks adjacent in x so the shared A-tile stays L2/L3 hot.
// ---------------------------------------------------------------------------
__global__ __launch_bounds__(256) void gemm_big(
    const float* __restrict__ A, const float* __restrict__ W,
    const float* __restrict__ bias, float* __restrict__ C)
{
    __shared__ __align__(16) float As[16][136];
    __shared__ __align__(16) float Ws[16][136];

    const int t  = threadIdx.x;
    const int m0 = blockIdx.y * 128;
    const int n0 = blockIdx.x * 128;
    const int tr = t >> 4, tc = t & 15;     // 16x16 thread grid, micro 8x8
    const int lr = t >> 2;                  // 0..63 (rows lr, lr+64)
    const int kq = (t & 3) * 4;             // k offset
    const int K  = DV;

    float4 aA0, aA1, aW0, aW1;
    auto gload = [&](int k0) {
        aA0 = *(const float4*)&A[(size_t)(m0 + lr) * K + k0 + kq];
        aA1 = *(const float4*)&A[(size_t)(m0 + lr + 64) * K + k0 + kq];
        aW0 = *(const float4*)&W[(size_t)(n0 + lr) * K + k0 + kq];
        aW1 = *(const float4*)&W[(size_t)(n0 + lr + 64) * K + k0 + kq];
    };
    gload(0);

    float acc[8][8] = {};

    for (int k0 = 0; k0 < K; k0 += 16) {
        __syncthreads();
        As[kq + 0][lr] = aA0.x; As[kq + 1][lr] = aA0.y;
        As[kq + 2][lr] = aA0.z; As[kq + 3][lr] = aA0.w;
        As[kq + 0][lr + 64] = aA1.x; As[kq + 1][lr + 64] = aA1.y;
        As[kq + 2][lr + 64] = aA1.z; As[kq + 3][lr + 64] = aA1.w;
        Ws[kq + 0][lr] = aW0.x; Ws[kq + 1][lr] = aW0.y;
        Ws[kq + 2][lr] = aW0.z; Ws[kq + 3][lr] = aW0.w;
        Ws[kq + 0][lr + 64] = aW1.x; Ws[kq + 1][lr + 64] = aW1.y;
        Ws[kq + 2][lr + 64] = aW1.z; Ws[kq + 3][lr + 64] = aW1.w;
        __syncthreads();
        if (k0 + 16 < K) gload(k0 + 16);
#pragma unroll
        for (int kk = 0; kk < 16; ++kk) {
            const float4 af0 = *(const float4*)&As[kk][tr * 8];
            const float4 af1 = *(const float4*)&As[kk][tr * 8 + 4];
            const float4 wf0 = *(const float4*)&Ws[kk][tc * 8];
            const float4 wf1 = *(const float4*)&Ws[kk][tc * 8 + 4];
            const float arr[8] = { af0.x, af0.y, af0.z, af0.w, af1.x, af1.y, af1.z, af1.w };
            const float wrr[8] = { wf0.x, wf0.y, wf0.z, wf0.w, wf1.x, wf1.y, wf1.z, wf1.w };
#pragma unroll
            for (int i = 0; i < 8; ++i)
#pragma unroll
                for (int j = 0; j < 8; ++j)
                    acc[i][j] = fmaf(arr[i], wrr[j], acc[i][j]);
        }
    }

#pragma unroll
    for (int i = 0; i < 8; ++i) {
        const int m = m0 + tr * 8 + i;
        float4 v0, v1;
        v0.x = acc[i][0] + bias[n0 + tc * 8 + 0];
        v0.y = acc[i][1] + bias[n0 + tc * 8 + 1];
        v0.z = acc[i][2] + bias[n0 + tc * 8 + 2];
        v0.w = acc[i][3] + bias[n0 + tc * 8 + 3];
        v1.x = acc[i][4] + bias[n0 + tc * 8 + 4];
        v1.y = acc[i][5] + bias[n0 + tc * 8 + 5];
        v1.z = acc[i][6] + bias[n0 + tc * 8 + 6];
        v1.w = acc[i][7] + bias[n0 + tc * 8 + 7];
        *(float4*)&C[(size_t)m * AT + n0 + tc * 8]     = v0;
        *(float4*)&C[(size_t)m * AT + n0 + tc * 8 + 4] = v1;
    }
}

// ---------------------------------------------------------------------------
// att_fused: per batch row b (one block):
//   dec = h[b] @ dec_att_w^T + b_dec                      (phase 1)
//   logit[n] = sum_a tanh(vis_att[b,n,a]+dec[a])*fw[a]+fb (phase 2)
//   sc = softmax(logit)                                   (phase 3)
//   att_out[b,:] = sum_n sc[n] * vis[b,n,:]               (phase 4)
// ---------------------------------------------------------------------------
__global__ __launch_bounds__(256) void att_fused(
    const float* __restrict__ vis_att, const float* __restrict__ h,
    const float* __restrict__ dec_w, const float* __restrict__ dec_b,
    const float* __restrict__ fw, const float* __restrict__ fbp,
    const float* __restrict__ vis, float* __restrict__ att_out)
{
    const int b = blockIdx.x;
    const int t = threadIdx.x;
    const int lane = t & 63;
    const int w = t >> 6;

    __shared__ float hs[HH];
    __shared__ float decs[AT];
    __shared__ float fwv[AT];
    __shared__ float logit[NR + 4];
    __shared__ float sc[NR + 4];
    __shared__ float red[16];

    // stage h[b] and fw
#pragma unroll
    for (int j = 0; j < 4; ++j) hs[t + 256 * j] = h[(size_t)b * HH + t + 256 * j];
    fwv[t] = fw[t];
    __syncthreads();
    const float fb = fbp[0];

    // phase 1: dec (each wave owns 64 outputs)
    for (int a0 = 0; a0 < 64; ++a0) {
        const int a = w * 64 + a0;
        const float* wr = dec_w + (size_t)a * HH;
        float p = 0.f;
#pragma unroll
        for (int i = 0; i < 16; ++i) p = fmaf(wr[i * 64 + lane], hs[i * 64 + lane], p);
        for (int off = 32; off; off >>= 1) p += __shfl_down(p, off);
        if (lane == 0) decs[a] = p + dec_b[a];
    }
    __syncthreads();

    // phase 2: logits (waves stride over regions)
    for (int n = w; n < NR; n += 4) {
        const float* va = vis_att + ((size_t)b * NR + n) * AT;
        float s = 0.f;
#pragma unroll
        for (int c = 0; c < 4; ++c) {
            const int a = c * 64 + lane;
            s = fmaf(tanhf(va[a] + decs[a]), fwv[a], s);
        }
        for (int off = 32; off; off >>= 1) s += __shfl_down(s, off);
        if (lane == 0) logit[n] = s + fb;
    }
    __syncthreads();

    // phase 3: softmax over NR
    float m = -1e30f;
    if (t < NR) m = logit[t];
    for (int off = 32; off; off >>= 1) m = fmaxf(m, __shfl_down(m, off));
    if (lane == 0) red[w] = m;
    __syncthreads();
    m = fmaxf(fmaxf(red[0], red[1]), fmaxf(red[2], red[3]));
    float e = 0.f;
    if (t < NR) e = expf(logit[t] - m);
    float ssum = e;
    for (int off = 32; off; off >>= 1) ssum += __shfl_down(ssum, off);
    if (lane == 0) red[8 + w] = ssum;
    __syncthreads();
    const float S = red[8] + red[9] + red[10] + red[11];
    if (t < NR) sc[t] = e / S;
    __syncthreads();

    // phase 4: att_out = sum_n sc[n] * vis[b,n,:]
    const float* vb = vis + (size_t)b * NR * DV;
    float a0 = 0.f, a1 = 0.f, a2 = 0.f, a3 = 0.f;
    for (int n = 0; n < NR; ++n) {
        const float scn = sc[n];
        const float* r = vb + (size_t)n * DV + t;
        a0 = fmaf(scn, r[0], a0);
        a1 = fmaf(scn, r[256], a1);
        a2 = fmaf(scn, r[512], a2);
        a3 = fmaf(scn, r[768], a3);
    }
    float* ob = att_out + (size_t)b * DV + t;
    ob[0] = a0; ob[256] = a1; ob[512] = a2; ob[768] = a3;
}

// ---------------------------------------------------------------------------
// LSTM pointwise, float4 per thread.
// ---------------------------------------------------------------------------
__global__ __launch_bounds__(256) void lstm_pw4(
    const float* __restrict__ gates, float* __restrict__ c, float* __restrict__ hnew)
{
    const int i4 = (blockIdx.x * 256 + threadIdx.x) * 4;
    const int b  = i4 >> 10;
    const int hh = i4 & 1023;
    const float* g = gates + (size_t)b * 4 * HH;
    const float4 gi = *(const float4*)&g[hh];
    const float4 gf = *(const float4*)&g[HH + hh];
    const float4 gg = *(const float4*)&g[2 * HH + hh];
    const float4 go = *(const float4*)&g[3 * HH + hh];
    float4 cv = *(float4*)&c[i4];
    float4 hv;
    cv.x = sigmoidf_(gf.x) * cv.x + sigmoidf_(gi.x) * tanhf(gg.x);
    cv.y = sigmoidf_(gf.y) * cv.y + sigmoidf_(gi.y) * tanhf(gg.y);
    cv.z = sigmoidf_(gf.z) * cv.z + sigmoidf_(gi.z) * tanhf(gg.z);
    cv.w = sigmoidf_(gf.w) * cv.w + sigmoidf_(gi.w) * tanhf(gg.w);
    hv.x = sigmoidf_(go.x) * tanhf(cv.x);
    hv.y = sigmoidf_(go.y) * tanhf(cv.y);
    hv.z = sigmoidf_(go.z) * tanhf(cv.z);
    hv.w = sigmoidf_(go.w) * tanhf(cv.w);
    *(float4*)&c[i4]    = cv;
    *(float4*)&hnew[i4] = hv;
}

// ---------------------------------------------------------------------------
// final stop projection: p[b,:] = pt[b,:] @ fw^T + fb (fw: [2, IS])
// ---------------------------------------------------------------------------
__global__ __launch_bounds__(256) void stop_final(
    const float* __restrict__ pt, const float* __restrict__ fw,
    const float* __restrict__ fb, float* __restrict__ outp)
{
    const int b = blockIdx.x;
    const int t = threadIdx.x;
    const int lane = t & 63;
    const int w = t >> 6;

    __shared__ float red[16];
    const float v = pt[b * IS + t];
    float p0 = v * fw[t];
    float p1 = v * fw[IS + t];
    for (int off = 32; off; off >>= 1) {
        p0 += __shfl_down(p0, off);
        p1 += __shfl_down(p1, off);
    }
    if (lane == 0) { red[w] = p0; red[8 + w] = p1; }
    __syncthreads();
    if (t == 0) {
        outp[(size_t)b * ST * 2 + 0] = red[0] + red[1] + red[2] + red[3] + fb[0];
        outp[(size_t)b * ST * 2 + 1] = red[8] + red[9] + red[10] + red[11] + fb[1];
    }
}

// ---------------------------------------------------------------------------
extern "C" void kernel_launch(void* const* d_in, const int* in_sizes, int n_in,
                              void* d_out, int out_size, void* d_ws, size_t ws_size,
                              hipStream_t stream)
{
    const float* vis        = (const float*)d_in[0];
    const float* enc_att_w  = (const float*)d_in[2];
    const float* enc_att_b  = (const float*)d_in[3];
    const float* dec_att_w  = (const float*)d_in[4];
    const float* dec_att_b  = (const float*)d_in[5];
    const float* full_att_w = (const float*)d_in[6];
    const float* full_att_b = (const float*)d_in[7];
    const float* ctx_w      = (const float*)d_in[8];
    const float* ctx_b      = (const float*)d_in[9];
    const float* W_ih       = (const float*)d_in[10];
    const float* b_ih       = (const float*)d_in[11];
    const float* W_hh       = (const float*)d_in[12];
    const float* b_hh       = (const float*)d_in[13];
    const float* topic_hid_w = (const float*)d_in[14];
    const float* topic_hid_b = (const float*)d_in[15];
    const float* topic_ctx_w = (const float*)d_in[16];
    const float* topic_ctx_b = (const float*)d_in[17];
    const float* stop_prev_w = (const float*)d_in[18];
    const float* stop_prev_b = (const float*)d_in[19];
    const float* stop_cur_w  = (const float*)d_in[20];
    const float* stop_cur_b  = (const float*)d_in[21];
    const float* final_stop_w = (const float*)d_in[22];
    const float* final_stop_b = (const float*)d_in[23];

    float* out_topics = (float*)d_out;                        // [B, ST, WI]
    float* out_ps     = (float*)d_out + (size_t)BB * ST * WI; // [B, ST, 2]

    char* ws = (char*)d_ws;
    size_t off = 0;
    auto alloc = [&](size_t bytes) -> float* {
        float* p = (float*)(ws + off);
        off += (bytes + 255) & ~(size_t)255;
        return p;
    };
    float* vis_att = alloc((size_t)BB * NR * AT * 4);  // 51.4 MB
    float* hA      = alloc((size_t)BB * HH * 4);
    float* hB      = alloc((size_t)BB * HH * 4);
    float* cbuf    = alloc((size_t)BB * HH * 4);
    float* att_out = alloc((size_t)BB * DV * 4);
    float* ctx     = alloc((size_t)BB * SI * 4);
    float* gates   = alloc((size_t)BB * 4 * HH * 4);
    float* pt      = alloc((size_t)BB * IS * 4);
    if (off > ws_size) return;

    hipMemsetAsync(hA, 0, (size_t)BB * HH * 4, stream);
    hipMemsetAsync(cbuf, 0, (size_t)BB * HH * 4, stream);

    // hoisted encoder projection
    gemm_big<<<dim3(AT / 128, (BB * NR) / 128), 256, 0, stream>>>(
        vis, enc_att_w, enc_att_b, vis_att);

    float* hc = hA;   // h_prev
    float* hn = hB;   // h_new
    for (int s = 0; s < ST; ++s) {
        att_fused<<<BB, 256, 0, stream>>>(vis_att, hc, dec_att_w, dec_att_b,
                                          full_att_w, full_att_b, vis, att_out);
        // ctx = att_out @ ctx_w^T + ctx_b
        gemm32<0, 0><<<dim3(SI / 32, BB / 64), 256, 0, stream>>>(
            att_out, ctx_w, ctx_b, nullptr, nullptr, nullptr,
            ctx, BB, SI, DV, SI);
        // gates = ctx @ W_ih^T + b_ih + h @ W_hh^T + b_hh
        gemm32<0, 1><<<dim3(4 * HH / 32, BB / 64), 256, 0, stream>>>(
            ctx, W_ih, b_ih, hc, W_hh, b_hh,
            gates, BB, 4 * HH, SI, 4 * HH);
        lstm_pw4<<<(BB * HH) / 1024, 256, 0, stream>>>(gates, cbuf, hn);
        // topic -> out
        gemm32<1, 1><<<dim3(WI / 32, BB / 64), 256, 0, stream>>>(
            hn, topic_hid_w, topic_hid_b, ctx, topic_ctx_w, topic_ctx_b,
            out_topics + (size_t)s * WI, BB, WI, HH, ST * WI);
        // stop inner
        gemm32<1, 1><<<dim3(IS / 32, BB / 64), 256, 0, stream>>>(
            hc, stop_prev_w, stop_prev_b, hn, stop_cur_w, stop_cur_b,
            pt, BB, IS, HH, IS);
        stop_final<<<BB, 256, 0, stream>>>(pt, final_stop_w, final_stop_b,
                                           out_ps + (size_t)s * 2);
        float* tmp = hc; hc = hn; hn = tmp;
    }
}

// Round 3
// 4120.225 us; speedup vs baseline: 1.6078x; 1.1895x over previous
//
#include <hip/hip_runtime.h>
#include <hip/hip_bf16.h>
#include <math.h>

// Problem constants (SentenceLSTM)
static constexpr int BB = 256;    // batch
static constexpr int NR = 196;    // regions
static constexpr int DV = 1024;   // vis embed dim
static constexpr int HH = 1024;   // hidden
static constexpr int AT = 256;    // att dim
static constexpr int SI = 1024;   // sem input dim (ctx)
static constexpr int WI = 1024;   // topic width
static constexpr int IS = 256;    // stop inner dim
static constexpr int ST = 10;     // sentence steps

__device__ __forceinline__ float sigmoidf_(float x) { return 1.0f / (1.0f + expf(-x)); }

// bf16 round-to-nearest-even, bit-level
__device__ __forceinline__ ushort f2bf(float x) {
    uint u = __float_as_uint(x);
    return (ushort)((u + 0x7FFFu + ((u >> 16) & 1u)) >> 16);
}
__device__ __forceinline__ float bf2f(ushort b) { return __uint_as_float(((uint)b) << 16); }

using bf16x8 = __attribute__((ext_vector_type(8))) short;
using f32x4  = __attribute__((ext_vector_type(4))) float;
#define MFMA_B16(a, b, c) __builtin_amdgcn_mfma_f32_16x16x32_bf16((a), (b), (c), 0, 0, 0)

// split 8 fp32 (two float4) into hi/lo bf16 packed as uint4 each
__device__ __forceinline__ void split8(const float4& u, const float4& v, uint4& hq, uint4& lq) {
    ushort h0 = f2bf(u.x), h1 = f2bf(u.y), h2 = f2bf(u.z), h3 = f2bf(u.w);
    ushort h4 = f2bf(v.x), h5 = f2bf(v.y), h6 = f2bf(v.z), h7 = f2bf(v.w);
    hq.x = h0 | ((uint)h1 << 16); hq.y = h2 | ((uint)h3 << 16);
    hq.z = h4 | ((uint)h5 << 16); hq.w = h6 | ((uint)h7 << 16);
    ushort l0 = f2bf(u.x - bf2f(h0)), l1 = f2bf(u.y - bf2f(h1));
    ushort l2 = f2bf(u.z - bf2f(h2)), l3 = f2bf(u.w - bf2f(h3));
    ushort l4 = f2bf(v.x - bf2f(h4)), l5 = f2bf(v.y - bf2f(h5));
    ushort l6 = f2bf(v.z - bf2f(h6)), l7 = f2bf(v.w - bf2f(h7));
    lq.x = l0 | ((uint)l1 << 16); lq.y = l2 | ((uint)l3 << 16);
    lq.z = l4 | ((uint)l5 << 16); lq.w = l6 | ((uint)l7 << 16);
}

// ---------------------------------------------------------------------------
// Weight fp32 -> (hi,lo) bf16 split conversion, all 9 weight matrices in one
// launch. Each block handles 1024 contiguous elements of one segment.
// ---------------------------------------------------------------------------
struct CvtTab { const float* s[9]; ushort* h[9]; ushort* l[9]; };

__global__ __launch_bounds__(256) void convert_split(CvtTab tab) {
    // cumulative blocks (1024 elems per block) per segment:
    // enc(256) dec(256) ctx(1024) ih(4096) hh(4096) th(1024) tc(1024) sp(256) sc(256)
    const int cum[10] = {0, 256, 512, 1536, 5632, 9728, 10752, 11776, 12032, 12288};
    const int bid = blockIdx.x;
    int seg = 0;
#pragma unroll
    for (int i = 1; i < 9; ++i) if (bid >= cum[i]) seg = i;
    const float* s = tab.s[seg];
    ushort* h = tab.h[seg];
    ushort* l = tab.l[seg];
    const int idx = (bid - cum[seg]) * 1024 + threadIdx.x * 4;
    float4 v = *(const float4*)(s + idx);
    ushort h0 = f2bf(v.x), h1 = f2bf(v.y), h2 = f2bf(v.z), h3 = f2bf(v.w);
    uint2 hq, lq;
    hq.x = h0 | ((uint)h1 << 16); hq.y = h2 | ((uint)h3 << 16);
    ushort l0 = f2bf(v.x - bf2f(h0)), l1 = f2bf(v.y - bf2f(h1));
    ushort l2 = f2bf(v.z - bf2f(h2)), l3 = f2bf(v.w - bf2f(h3));
    lq.x = l0 | ((uint)l1 << 16); lq.y = l2 | ((uint)l3 << 16);
    *(uint2*)(h + idx) = hq;
    *(uint2*)(l + idx) = lq;
}

// ---------------------------------------------------------------------------
// mgemm: C = act( A1*W1^T + b1 [+ A2*W2^T + b2] ) via split-bf16 MFMA.
// A fp32 [M,K] rm (split in staging); W pre-split bf16 hi/lo [N,K] rm.
// Tile 64x64, 4 waves (wave w owns cols w*16..+15), BK=32, 3 MFMA terms.
// LDS rows padded to 40 shorts (80 B) -> 2-way bank conflicts only (free).
// ---------------------------------------------------------------------------
template <int ACT, int DUAL>
__global__ __launch_bounds__(256) void mgemm(
    const float* __restrict__ A1, const ushort* __restrict__ W1h, const ushort* __restrict__ W1l,
    const float* __restrict__ b1,
    const float* __restrict__ A2, const ushort* __restrict__ W2h, const ushort* __restrict__ W2l,
    const float* __restrict__ b2,
    float* __restrict__ C, int M, int N, int K, int ldc)
{
    __shared__ __align__(16) ushort Ah[64 * 40], Al[64 * 40], Bh[64 * 40], Bl[64 * 40];

    const int t = threadIdx.x;
    const int m0 = blockIdx.y * 64, n0 = blockIdx.x * 64;
    const int w = t >> 6, lane = t & 63;
    const int l15 = lane & 15, q = lane >> 4;
    const int sr = t >> 2, sq = (t & 3) * 8;
    const int KC = K >> 5, nch = (DUAL ? 2 : 1) * KC;

    f32x4 acc[4] = {};
    float4 pa0, pa1; uint4 pbh, pbl;

    auto pref = [&](int c) {
        const int pass = DUAL ? (c >= KC ? 1 : 0) : 0;
        const int k0 = (c - pass * KC) << 5;
        const float* A = pass ? A2 : A1;
        const ushort* Wh = pass ? W2h : W1h;
        const ushort* Wl = pass ? W2l : W1l;
        const float* ap = &A[(size_t)(m0 + sr) * K + k0 + sq];
        pa0 = *(const float4*)ap;
        pa1 = *(const float4*)(ap + 4);
        pbh = *(const uint4*)&Wh[(size_t)(n0 + sr) * K + k0 + sq];
        pbl = *(const uint4*)&Wl[(size_t)(n0 + sr) * K + k0 + sq];
    };
    pref(0);

    for (int c = 0; c < nch; ++c) {
        __syncthreads();
        uint4 hq, lq; split8(pa0, pa1, hq, lq);
        *(uint4*)&Ah[sr * 40 + sq] = hq;
        *(uint4*)&Al[sr * 40 + sq] = lq;
        *(uint4*)&Bh[sr * 40 + sq] = pbh;
        *(uint4*)&Bl[sr * 40 + sq] = pbl;
        __syncthreads();
        if (c + 1 < nch) pref(c + 1);
        const bf16x8 bh = *(const bf16x8*)&Bh[(w * 16 + l15) * 40 + q * 8];
        const bf16x8 bl = *(const bf16x8*)&Bl[(w * 16 + l15) * 40 + q * 8];
#pragma unroll
        for (int mi = 0; mi < 4; ++mi) {
            const bf16x8 ah = *(const bf16x8*)&Ah[(mi * 16 + l15) * 40 + q * 8];
            const bf16x8 al = *(const bf16x8*)&Al[(mi * 16 + l15) * 40 + q * 8];
            acc[mi] = MFMA_B16(ah, bh, acc[mi]);
            acc[mi] = MFMA_B16(ah, bl, acc[mi]);
            acc[mi] = MFMA_B16(al, bh, acc[mi]);
        }
    }

    const int col = n0 + w * 16 + l15;
    float bias = b1[col];
    if (DUAL) bias += b2[col];
#pragma unroll
    for (int mi = 0; mi < 4; ++mi) {
#pragma unroll
        for (int j = 0; j < 4; ++j) {
            const int row = m0 + mi * 16 + q * 4 + j;
            float v = acc[mi][j] + bias;
            if (ACT) v = tanhf(v);
            C[(size_t)row * ldc + col] = v;
        }
    }
}

// ---------------------------------------------------------------------------
// mgemm_pre: vis_att = vis @ enc_att_w^T + b.  M=BB*NR, N=256 (full), K=1024.
// Tile 64x256 (wave w owns cols w*64..+63): A fp32 read exactly once.
// B (enc hi/lo, 1 MB) is re-read per chunk but L2-resident.
// ---------------------------------------------------------------------------
__global__ __launch_bounds__(256) void mgemm_pre(
    const float* __restrict__ A, const ushort* __restrict__ Wh, const ushort* __restrict__ Wl,
    const float* __restrict__ bias, float* __restrict__ C)
{
    __shared__ __align__(16) ushort Ah[64 * 40], Al[64 * 40];
    __shared__ __align__(16) ushort Bh[256 * 40], Bl[256 * 40];

    const int t = threadIdx.x;
    const int m0 = blockIdx.x * 64;
    const int w = t >> 6, lane = t & 63;
    const int l15 = lane & 15, q = lane >> 4;
    const int sr = t >> 2, sq = (t & 3) * 8;
    const int K = DV;

    f32x4 acc[4][4] = {};
    float4 pa0, pa1;
    auto prefA = [&](int k0) {
        const float* ap = &A[(size_t)(m0 + sr) * K + k0 + sq];
        pa0 = *(const float4*)ap;
        pa1 = *(const float4*)(ap + 4);
    };
    prefA(0);

    for (int c = 0; c < 32; ++c) {
        const int k0 = c << 5;
        __syncthreads();
        uint4 hq, lq; split8(pa0, pa1, hq, lq);
        *(uint4*)&Ah[sr * 40 + sq] = hq;
        *(uint4*)&Al[sr * 40 + sq] = lq;
#pragma unroll
        for (int i = 0; i < 4; ++i) {
            const int r = sr + 64 * i;
            *(uint4*)&Bh[r * 40 + sq] = *(const uint4*)&Wh[(size_t)r * K + k0 + sq];
            *(uint4*)&Bl[r * 40 + sq] = *(const uint4*)&Wl[(size_t)r * K + k0 + sq];
        }
        __syncthreads();
        if (c + 1 < 32) prefA((c + 1) << 5);

        bf16x8 ah[4], al[4];
#pragma unroll
        for (int mi = 0; mi < 4; ++mi) {
            ah[mi] = *(const bf16x8*)&Ah[(mi * 16 + l15) * 40 + q * 8];
            al[mi] = *(const bf16x8*)&Al[(mi * 16 + l15) * 40 + q * 8];
        }
#pragma unroll
        for (int ni = 0; ni < 4; ++ni) {
            const bf16x8 bh = *(const bf16x8*)&Bh[(w * 64 + ni * 16 + l15) * 40 + q * 8];
            const bf16x8 bl = *(const bf16x8*)&Bl[(w * 64 + ni * 16 + l15) * 40 + q * 8];
#pragma unroll
            for (int mi = 0; mi < 4; ++mi) {
                acc[mi][ni] = MFMA_B16(ah[mi], bh, acc[mi][ni]);
                acc[mi][ni] = MFMA_B16(ah[mi], bl, acc[mi][ni]);
                acc[mi][ni] = MFMA_B16(al[mi], bh, acc[mi][ni]);
            }
        }
    }

#pragma unroll
    for (int ni = 0; ni < 4; ++ni) {
        const int col = w * 64 + ni * 16 + l15;
        const float bb = bias[col];
#pragma unroll
        for (int mi = 0; mi < 4; ++mi)
#pragma unroll
            for (int j = 0; j < 4; ++j) {
                const int row = m0 + mi * 16 + q * 4 + j;
                C[(size_t)row * AT + col] = acc[mi][ni][j] + bb;
            }
    }
}

// ---------------------------------------------------------------------------
// att_fused: per batch row b (one block): dec proj + logits + softmax + apply
// ---------------------------------------------------------------------------
__global__ __launch_bounds__(256) void att_fused(
    const float* __restrict__ vis_att, const float* __restrict__ h,
    const float* __restrict__ dec_w, const float* __restrict__ dec_b,
    const float* __restrict__ fw, const float* __restrict__ fbp,
    const float* __restrict__ vis, float* __restrict__ att_out)
{
    const int b = blockIdx.x;
    const int t = threadIdx.x;
    const int lane = t & 63;
    const int w = t >> 6;

    __shared__ float hs[HH];
    __shared__ float decs[AT];
    __shared__ float fwv[AT];
    __shared__ float logit[NR + 4];
    __shared__ float sc[NR + 4];
    __shared__ float red[16];

#pragma unroll
    for (int j = 0; j < 4; ++j) hs[t + 256 * j] = h[(size_t)b * HH + t + 256 * j];
    fwv[t] = fw[t];
    __syncthreads();
    const float fb = fbp[0];

    // phase 1: dec (each wave owns 64 outputs)
    for (int a0 = 0; a0 < 64; ++a0) {
        const int a = w * 64 + a0;
        const float* wr = dec_w + (size_t)a * HH;
        float p = 0.f;
#pragma unroll
        for (int i = 0; i < 16; ++i) p = fmaf(wr[i * 64 + lane], hs[i * 64 + lane], p);
        for (int off = 32; off; off >>= 1) p += __shfl_down(p, off);
        if (lane == 0) decs[a] = p + dec_b[a];
    }
    __syncthreads();

    // phase 2: logits
    for (int n = w; n < NR; n += 4) {
        const float* va = vis_att + ((size_t)b * NR + n) * AT;
        float s = 0.f;
#pragma unroll
        for (int c = 0; c < 4; ++c) {
            const int a = c * 64 + lane;
            s = fmaf(tanhf(va[a] + decs[a]), fwv[a], s);
        }
        for (int off = 32; off; off >>= 1) s += __shfl_down(s, off);
        if (lane == 0) logit[n] = s + fb;
    }
    __syncthreads();

    // phase 3: softmax over NR
    float m = -1e30f;
    if (t < NR) m = logit[t];
    for (int off = 32; off; off >>= 1) m = fmaxf(m, __shfl_down(m, off));
    if (lane == 0) red[w] = m;
    __syncthreads();
    m = fmaxf(fmaxf(red[0], red[1]), fmaxf(red[2], red[3]));
    float e = 0.f;
    if (t < NR) e = expf(logit[t] - m);
    float ssum = e;
    for (int off = 32; off; off >>= 1) ssum += __shfl_down(ssum, off);
    if (lane == 0) red[8 + w] = ssum;
    __syncthreads();
    const float S = red[8] + red[9] + red[10] + red[11];
    if (t < NR) sc[t] = e / S;
    __syncthreads();

    // phase 4: att_out = sum_n sc[n] * vis[b,n,:]
    const float* vb = vis + (size_t)b * NR * DV;
    float a0 = 0.f, a1 = 0.f, a2 = 0.f, a3 = 0.f;
    for (int n = 0; n < NR; ++n) {
        const float scn = sc[n];
        const float* r = vb + (size_t)n * DV + t;
        a0 = fmaf(scn, r[0], a0);
        a1 = fmaf(scn, r[256], a1);
        a2 = fmaf(scn, r[512], a2);
        a3 = fmaf(scn, r[768], a3);
    }
    float* ob = att_out + (size_t)b * DV + t;
    ob[0] = a0; ob[256] = a1; ob[512] = a2; ob[768] = a3;
}

// ---------------------------------------------------------------------------
// LSTM pointwise, float4 per thread.
// ---------------------------------------------------------------------------
__global__ __launch_bounds__(256) void lstm_pw4(
    const float* __restrict__ gates, float* __restrict__ c, float* __restrict__ hnew)
{
    const int i4 = (blockIdx.x * 256 + threadIdx.x) * 4;
    const int b  = i4 >> 10;
    const int hh = i4 & 1023;
    const float* g = gates + (size_t)b * 4 * HH;
    const float4 gi = *(const float4*)&g[hh];
    const float4 gf = *(const float4*)&g[HH + hh];
    const float4 gg = *(const float4*)&g[2 * HH + hh];
    const float4 go = *(const float4*)&g[3 * HH + hh];
    float4 cv = *(float4*)&c[i4];
    float4 hv;
    cv.x = sigmoidf_(gf.x) * cv.x + sigmoidf_(gi.x) * tanhf(gg.x);
    cv.y = sigmoidf_(gf.y) * cv.y + sigmoidf_(gi.y) * tanhf(gg.y);
    cv.z = sigmoidf_(gf.z) * cv.z + sigmoidf_(gi.z) * tanhf(gg.z);
    cv.w = sigmoidf_(gf.w) * cv.w + sigmoidf_(gi.w) * tanhf(gg.w);
    hv.x = sigmoidf_(go.x) * tanhf(cv.x);
    hv.y = sigmoidf_(go.y) * tanhf(cv.y);
    hv.z = sigmoidf_(go.z) * tanhf(cv.z);
    hv.w = sigmoidf_(go.w) * tanhf(cv.w);
    *(float4*)&c[i4]    = cv;
    *(float4*)&hnew[i4] = hv;
}

// ---------------------------------------------------------------------------
// final stop projection: p[b,:] = pt[b,:] @ fw^T + fb (fw: [2, IS])
// ---------------------------------------------------------------------------
__global__ __launch_bounds__(256) void stop_final(
    const float* __restrict__ pt, const float* __restrict__ fw,
    const float* __restrict__ fb, float* __restrict__ outp)
{
    const int b = blockIdx.x;
    const int t = threadIdx.x;
    const int lane = t & 63;
    const int w = t >> 6;

    __shared__ float red[16];
    const float v = pt[b * IS + t];
    float p0 = v * fw[t];
    float p1 = v * fw[IS + t];
    for (int off = 32; off; off >>= 1) {
        p0 += __shfl_down(p0, off);
        p1 += __shfl_down(p1, off);
    }
    if (lane == 0) { red[w] = p0; red[8 + w] = p1; }
    __syncthreads();
    if (t == 0) {
        outp[(size_t)b * ST * 2 + 0] = red[0] + red[1] + red[2] + red[3] + fb[0];
        outp[(size_t)b * ST * 2 + 1] = red[8] + red[9] + red[10] + red[11] + fb[1];
    }
}

// ---------------------------------------------------------------------------
extern "C" void kernel_launch(void* const* d_in, const int* in_sizes, int n_in,
                              void* d_out, int out_size, void* d_ws, size_t ws_size,
                              hipStream_t stream)
{
    const float* vis        = (const float*)d_in[0];
    const float* enc_att_w  = (const float*)d_in[2];
    const float* enc_att_b  = (const float*)d_in[3];
    const float* dec_att_w  = (const float*)d_in[4];
    const float* dec_att_b  = (const float*)d_in[5];
    const float* full_att_w = (const float*)d_in[6];
    const float* full_att_b = (const float*)d_in[7];
    const float* ctx_w      = (const float*)d_in[8];
    const float* ctx_b      = (const float*)d_in[9];
    const float* W_ih       = (const float*)d_in[10];
    const float* b_ih       = (const float*)d_in[11];
    const float* W_hh       = (const float*)d_in[12];
    const float* b_hh       = (const float*)d_in[13];
    const float* topic_hid_w = (const float*)d_in[14];
    const float* topic_hid_b = (const float*)d_in[15];
    const float* topic_ctx_w = (const float*)d_in[16];
    const float* topic_ctx_b = (const float*)d_in[17];
    const float* stop_prev_w = (const float*)d_in[18];
    const float* stop_prev_b = (const float*)d_in[19];
    const float* stop_cur_w  = (const float*)d_in[20];
    const float* stop_cur_b  = (const float*)d_in[21];
    const float* final_stop_w = (const float*)d_in[22];
    const float* final_stop_b = (const float*)d_in[23];

    float* out_topics = (float*)d_out;                        // [B, ST, WI]
    float* out_ps     = (float*)d_out + (size_t)BB * ST * WI; // [B, ST, 2]

    char* ws = (char*)d_ws;
    size_t off = 0;
    auto alloc = [&](size_t bytes) -> void* {
        void* p = (void*)(ws + off);
        off += (bytes + 255) & ~(size_t)255;
        return p;
    };
    float* vis_att = (float*)alloc((size_t)BB * NR * AT * 4);   // 51.4 MB
    // split-bf16 weight pool: 12,582,912 elems (hi and lo)
    const size_t WTOT = 12582912;
    ushort* wh = (ushort*)alloc(WTOT * 2);                      // 25.2 MB
    ushort* wl = (ushort*)alloc(WTOT * 2);                      // 25.2 MB
    float* hA      = (float*)alloc((size_t)BB * HH * 4);
    float* hB      = (float*)alloc((size_t)BB * HH * 4);
    float* cbuf    = (float*)alloc((size_t)BB * HH * 4);
    float* att_out = (float*)alloc((size_t)BB * DV * 4);
    float* ctx     = (float*)alloc((size_t)BB * SI * 4);
    float* gates   = (float*)alloc((size_t)BB * 4 * HH * 4);
    float* pt      = (float*)alloc((size_t)BB * IS * 4);
    if (off > ws_size) return;  // workspace too small — fail visibly

    // weight segment offsets (elements) within the pool
    const size_t O_ENC = 0;          // 256x1024
    const size_t O_DEC = 262144;     // 256x1024
    const size_t O_CTX = 524288;     // 1024x1024
    const size_t O_IH  = 1572864;    // 4096x1024
    const size_t O_HH  = 5767168;    // 4096x1024
    const size_t O_TH  = 9961472;    // 1024x1024
    const size_t O_TC  = 11010048;   // 1024x1024
    const size_t O_SP  = 12058624;   // 256x1024
    const size_t O_SC  = 12320768;   // 256x1024

    CvtTab tab;
    const float* srcs[9] = {enc_att_w, dec_att_w, ctx_w, W_ih, W_hh,
                            topic_hid_w, topic_ctx_w, stop_prev_w, stop_cur_w};
    const size_t offs[9] = {O_ENC, O_DEC, O_CTX, O_IH, O_HH, O_TH, O_TC, O_SP, O_SC};
    for (int i = 0; i < 9; ++i) {
        tab.s[i] = srcs[i];
        tab.h[i] = wh + offs[i];
        tab.l[i] = wl + offs[i];
    }

    hipMemsetAsync(hA, 0, (size_t)BB * HH * 4, stream);
    hipMemsetAsync(cbuf, 0, (size_t)BB * HH * 4, stream);

    convert_split<<<12288, 256, 0, stream>>>(tab);

    // hoisted encoder projection (A read once; B L2-resident)
    mgemm_pre<<<(BB * NR) / 64, 256, 0, stream>>>(
        vis, wh + O_ENC, wl + O_ENC, enc_att_b, vis_att);

    float* hc = hA;   // h_prev
    float* hn = hB;   // h_new
    for (int s = 0; s < ST; ++s) {
        att_fused<<<BB, 256, 0, stream>>>(vis_att, hc, dec_att_w, dec_att_b,
                                          full_att_w, full_att_b, vis, att_out);
        // ctx = att_out @ ctx_w^T + ctx_b
        mgemm<0, 0><<<dim3(SI / 64, BB / 64), 256, 0, stream>>>(
            att_out, wh + O_CTX, wl + O_CTX, ctx_b,
            nullptr, nullptr, nullptr, nullptr,
            ctx, BB, SI, DV, SI);
        // gates = ctx @ W_ih^T + b_ih + h @ W_hh^T + b_hh
        mgemm<0, 1><<<dim3(4 * HH / 64, BB / 64), 256, 0, stream>>>(
            ctx, wh + O_IH, wl + O_IH, b_ih,
            hc, wh + O_HH, wl + O_HH, b_hh,
            gates, BB, 4 * HH, SI, 4 * HH);
        lstm_pw4<<<(BB * HH) / 1024, 256, 0, stream>>>(gates, cbuf, hn);
        // topic -> out
        mgemm<1, 1><<<dim3(WI / 64, BB / 64), 256, 0, stream>>>(
            hn, wh + O_TH, wl + O_TH, topic_hid_b,
            ctx, wh + O_TC, wl + O_TC, topic_ctx_b,
            out_topics + (size_t)s * WI, BB, WI, HH, ST * WI);
        // stop inner
        mgemm<1, 1><<<dim3(IS / 64, BB / 64), 256, 0, stream>>>(
            hc, wh + O_SP, wl + O_SP, stop_prev_b,
            hn, wh + O_SC, wl + O_SC, stop_cur_b,
            pt, BB, IS, HH, IS);
        stop_final<<<BB, 256, 0, stream>>>(pt, final_stop_w, final_stop_b,
                                           out_ps + (size_t)s * 2);
        float* tmp = hc; hc = hn; hn = tmp;
    }
}

// Round 4
// 2843.165 us; speedup vs baseline: 2.3300x; 1.4492x over previous
//
#include <hip/hip_runtime.h>
#include <hip/hip_bf16.h>
#include <math.h>

// Problem constants (SentenceLSTM)
static constexpr int BB = 256;    // batch
static constexpr int NR = 196;    // regions
static constexpr int DV = 1024;   // vis embed dim
static constexpr int HH = 1024;   // hidden
static constexpr int AT = 256;    // att dim
static constexpr int SI = 1024;   // sem input dim (ctx)
static constexpr int WI = 1024;   // topic width
static constexpr int IS = 256;    // stop inner dim
static constexpr int ST = 10;     // sentence steps

__device__ __forceinline__ float sigmoidf_(float x) { return 1.0f / (1.0f + expf(-x)); }

// bf16 round-to-nearest-even, bit-level
__device__ __forceinline__ ushort f2bf(float x) {
    uint u = __float_as_uint(x);
    return (ushort)((u + 0x7FFFu + ((u >> 16) & 1u)) >> 16);
}
__device__ __forceinline__ float bf2f(ushort b) { return __uint_as_float(((uint)b) << 16); }

using bf16x8 = __attribute__((ext_vector_type(8))) short;
using f32x4  = __attribute__((ext_vector_type(4))) float;
#define MFMA_B16(a, b, c) __builtin_amdgcn_mfma_f32_16x16x32_bf16((a), (b), (c), 0, 0, 0)

// split 8 fp32 (two float4) into hi/lo bf16 packed as uint4 each
__device__ __forceinline__ void split8(const float4& u, const float4& v, uint4& hq, uint4& lq) {
    ushort h0 = f2bf(u.x), h1 = f2bf(u.y), h2 = f2bf(u.z), h3 = f2bf(u.w);
    ushort h4 = f2bf(v.x), h5 = f2bf(v.y), h6 = f2bf(v.z), h7 = f2bf(v.w);
    hq.x = h0 | ((uint)h1 << 16); hq.y = h2 | ((uint)h3 << 16);
    hq.z = h4 | ((uint)h5 << 16); hq.w = h6 | ((uint)h7 << 16);
    ushort l0 = f2bf(u.x - bf2f(h0)), l1 = f2bf(u.y - bf2f(h1));
    ushort l2 = f2bf(u.z - bf2f(h2)), l3 = f2bf(u.w - bf2f(h3));
    ushort l4 = f2bf(v.x - bf2f(h4)), l5 = f2bf(v.y - bf2f(h5));
    ushort l6 = f2bf(v.z - bf2f(h6)), l7 = f2bf(v.w - bf2f(h7));
    lq.x = l0 | ((uint)l1 << 16); lq.y = l2 | ((uint)l3 << 16);
    lq.z = l4 | ((uint)l5 << 16); lq.w = l6 | ((uint)l7 << 16);
}

// ---------------------------------------------------------------------------
// Weight fp32 -> (hi,lo) bf16 split conversion, all 9 weight matrices.
// ---------------------------------------------------------------------------
struct CvtTab { const float* s[9]; ushort* h[9]; ushort* l[9]; };

__global__ __launch_bounds__(256) void convert_split(CvtTab tab) {
    const int cum[10] = {0, 256, 512, 1536, 5632, 9728, 10752, 11776, 12032, 12288};
    const int bid = blockIdx.x;
    int seg = 0;
#pragma unroll
    for (int i = 1; i < 9; ++i) if (bid >= cum[i]) seg = i;
    const float* s = tab.s[seg];
    ushort* h = tab.h[seg];
    ushort* l = tab.l[seg];
    const int idx = (bid - cum[seg]) * 1024 + threadIdx.x * 4;
    float4 v = *(const float4*)(s + idx);
    ushort h0 = f2bf(v.x), h1 = f2bf(v.y), h2 = f2bf(v.z), h3 = f2bf(v.w);
    uint2 hq, lq;
    hq.x = h0 | ((uint)h1 << 16); hq.y = h2 | ((uint)h3 << 16);
    ushort l0 = f2bf(v.x - bf2f(h0)), l1 = f2bf(v.y - bf2f(h1));
    ushort l2 = f2bf(v.z - bf2f(h2)), l3 = f2bf(v.w - bf2f(h3));
    lq.x = l0 | ((uint)l1 << 16); lq.y = l2 | ((uint)l3 << 16);
    *(uint2*)(h + idx) = hq;
    *(uint2*)(l + idx) = lq;
}

// ---------------------------------------------------------------------------
// mgemm: C(fp32) = act( A1*W1^T + b1 [+ A2*W2^T + b2] ) via split-bf16 MFMA.
// ---------------------------------------------------------------------------
template <int ACT, int DUAL>
__global__ __launch_bounds__(256) void mgemm(
    const float* __restrict__ A1, const ushort* __restrict__ W1h, const ushort* __restrict__ W1l,
    const float* __restrict__ b1,
    const float* __restrict__ A2, const ushort* __restrict__ W2h, const ushort* __restrict__ W2l,
    const float* __restrict__ b2,
    float* __restrict__ C, int M, int N, int K, int ldc)
{
    __shared__ __align__(16) ushort Ah[64 * 40], Al[64 * 40], Bh[64 * 40], Bl[64 * 40];

    const int t = threadIdx.x;
    const int m0 = blockIdx.y * 64, n0 = blockIdx.x * 64;
    const int w = t >> 6, lane = t & 63;
    const int l15 = lane & 15, q = lane >> 4;
    const int sr = t >> 2, sq = (t & 3) * 8;
    const int KC = K >> 5, nch = (DUAL ? 2 : 1) * KC;

    f32x4 acc[4] = {};
    float4 pa0, pa1; uint4 pbh, pbl;

    auto pref = [&](int c) {
        const int pass = DUAL ? (c >= KC ? 1 : 0) : 0;
        const int k0 = (c - pass * KC) << 5;
        const float* A = pass ? A2 : A1;
        const ushort* Wh = pass ? W2h : W1h;
        const ushort* Wl = pass ? W2l : W1l;
        const float* ap = &A[(size_t)(m0 + sr) * K + k0 + sq];
        pa0 = *(const float4*)ap;
        pa1 = *(const float4*)(ap + 4);
        pbh = *(const uint4*)&Wh[(size_t)(n0 + sr) * K + k0 + sq];
        pbl = *(const uint4*)&Wl[(size_t)(n0 + sr) * K + k0 + sq];
    };
    pref(0);

    for (int c = 0; c < nch; ++c) {
        __syncthreads();
        uint4 hq, lq; split8(pa0, pa1, hq, lq);
        *(uint4*)&Ah[sr * 40 + sq] = hq;
        *(uint4*)&Al[sr * 40 + sq] = lq;
        *(uint4*)&Bh[sr * 40 + sq] = pbh;
        *(uint4*)&Bl[sr * 40 + sq] = pbl;
        __syncthreads();
        if (c + 1 < nch) pref(c + 1);
        const bf16x8 bh = *(const bf16x8*)&Bh[(w * 16 + l15) * 40 + q * 8];
        const bf16x8 bl = *(const bf16x8*)&Bl[(w * 16 + l15) * 40 + q * 8];
#pragma unroll
        for (int mi = 0; mi < 4; ++mi) {
            const bf16x8 ah = *(const bf16x8*)&Ah[(mi * 16 + l15) * 40 + q * 8];
            const bf16x8 al = *(const bf16x8*)&Al[(mi * 16 + l15) * 40 + q * 8];
            acc[mi] = MFMA_B16(ah, bh, acc[mi]);
            acc[mi] = MFMA_B16(ah, bl, acc[mi]);
            acc[mi] = MFMA_B16(al, bh, acc[mi]);
        }
    }

    const int col = n0 + w * 16 + l15;
    float bias = b1[col];
    if (DUAL) bias += b2[col];
#pragma unroll
    for (int mi = 0; mi < 4; ++mi) {
#pragma unroll
        for (int j = 0; j < 4; ++j) {
            const int row = m0 + mi * 16 + q * 4 + j;
            float v = acc[mi][j] + bias;
            if (ACT) v = tanhf(v);
            C[(size_t)row * ldc + col] = v;
        }
    }
}

// ---------------------------------------------------------------------------
// mgemm_pre: vis_att(bf16) = vis @ enc_att_w^T + b.  Also (WRITE_VBF) emits
// vis_bf = bf16(vis) as a side product of staging (each element read once).
// Tile 64x256, wave w owns cols w*64..+63.
// ---------------------------------------------------------------------------
template <int WRITE_VBF>
__global__ __launch_bounds__(256) void mgemm_pre(
    const float* __restrict__ A, const ushort* __restrict__ Wh, const ushort* __restrict__ Wl,
    const float* __restrict__ bias, ushort* __restrict__ C, ushort* __restrict__ vbf)
{
    __shared__ __align__(16) ushort Ah[64 * 40], Al[64 * 40];
    __shared__ __align__(16) ushort Bh[256 * 40], Bl[256 * 40];

    const int t = threadIdx.x;
    const int m0 = blockIdx.x * 64;
    const int w = t >> 6, lane = t & 63;
    const int l15 = lane & 15, q = lane >> 4;
    const int sr = t >> 2, sq = (t & 3) * 8;
    const int K = DV;

    f32x4 acc[4][4] = {};
    float4 pa0, pa1;
    auto prefA = [&](int k0) {
        const float* ap = &A[(size_t)(m0 + sr) * K + k0 + sq];
        pa0 = *(const float4*)ap;
        pa1 = *(const float4*)(ap + 4);
    };
    prefA(0);

    for (int c = 0; c < 32; ++c) {
        const int k0 = c << 5;
        __syncthreads();
        uint4 hq, lq; split8(pa0, pa1, hq, lq);
        *(uint4*)&Ah[sr * 40 + sq] = hq;
        *(uint4*)&Al[sr * 40 + sq] = lq;
        if (WRITE_VBF)
            *(uint4*)&vbf[(size_t)(m0 + sr) * K + k0 + sq] = hq;
#pragma unroll
        for (int i = 0; i < 4; ++i) {
            const int r = sr + 64 * i;
            *(uint4*)&Bh[r * 40 + sq] = *(const uint4*)&Wh[(size_t)r * K + k0 + sq];
            *(uint4*)&Bl[r * 40 + sq] = *(const uint4*)&Wl[(size_t)r * K + k0 + sq];
        }
        __syncthreads();
        if (c + 1 < 32) prefA((c + 1) << 5);

        bf16x8 ah[4], al[4];
#pragma unroll
        for (int mi = 0; mi < 4; ++mi) {
            ah[mi] = *(const bf16x8*)&Ah[(mi * 16 + l15) * 40 + q * 8];
            al[mi] = *(const bf16x8*)&Al[(mi * 16 + l15) * 40 + q * 8];
        }
#pragma unroll
        for (int ni = 0; ni < 4; ++ni) {
            const bf16x8 bh = *(const bf16x8*)&Bh[(w * 64 + ni * 16 + l15) * 40 + q * 8];
            const bf16x8 bl = *(const bf16x8*)&Bl[(w * 64 + ni * 16 + l15) * 40 + q * 8];
#pragma unroll
            for (int mi = 0; mi < 4; ++mi) {
                acc[mi][ni] = MFMA_B16(ah[mi], bh, acc[mi][ni]);
                acc[mi][ni] = MFMA_B16(ah[mi], bl, acc[mi][ni]);
                acc[mi][ni] = MFMA_B16(al[mi], bh, acc[mi][ni]);
            }
        }
    }

#pragma unroll
    for (int ni = 0; ni < 4; ++ni) {
        const int col = w * 64 + ni * 16 + l15;
        const float bb = bias[col];
#pragma unroll
        for (int mi = 0; mi < 4; ++mi)
#pragma unroll
            for (int j = 0; j < 4; ++j) {
                const int row = m0 + mi * 16 + q * 4 + j;
                C[(size_t)row * AT + col] = f2bf(acc[mi][ni][j] + bb);
            }
    }
}

// ---------------------------------------------------------------------------
// att_step: per batch row b (one 1024-thread block):
//   logit[n] = sum_a tanh(vis_att[b,n,a]+dec[b,a])*fw[a]+fb   (16 waves)
//   sc = softmax(logit)                                        (4 waves)
//   att_out[b,:] = sum_n sc[n]*vis[b,n,:]   (2-way n-split + LDS combine)
// VBF=1: vis is bf16 (ushort); VBF=0: vis is fp32.
// ---------------------------------------------------------------------------
template <int VBF>
__global__ __launch_bounds__(1024) void att_step(
    const ushort* __restrict__ vis_att, const float* __restrict__ dec,
    const float* __restrict__ fw, const float* __restrict__ fbp,
    const void* __restrict__ visp, float* __restrict__ att_out)
{
    const int b = blockIdx.x;
    const int t = threadIdx.x;
    const int lane = t & 63;
    const int w = t >> 6;

    __shared__ float decs[AT];
    __shared__ float fwv[AT];
    __shared__ float logit[NR + 4];
    __shared__ float sc[NR + 4];
    __shared__ float red[8];
    __shared__ float part[2][DV];

    if (t < AT) { decs[t] = dec[b * AT + t]; fwv[t] = fw[t]; }
    __syncthreads();
    const float fb = fbp[0];

    // phase 1: logits — wave w handles rows n = w, w+16, ...
    for (int n = w; n < NR; n += 16) {
        const ushort4 v4 = *(const ushort4*)&vis_att[((size_t)b * NR + n) * AT + lane * 4];
        const int a = lane * 4;
        float s = tanhf(bf2f(v4.x) + decs[a]) * fwv[a];
        s = fmaf(tanhf(bf2f(v4.y) + decs[a + 1]), fwv[a + 1], s);
        s = fmaf(tanhf(bf2f(v4.z) + decs[a + 2]), fwv[a + 2], s);
        s = fmaf(tanhf(bf2f(v4.w) + decs[a + 3]), fwv[a + 3], s);
        for (int off = 32; off; off >>= 1) s += __shfl_down(s, off);
        if (lane == 0) logit[n] = s + fb;
    }
    __syncthreads();

    // phase 2: softmax (first 4 waves)
    float m = -1e30f, e = 0.f;
    if (t < NR) m = logit[t];
    if (t < 256) {
        for (int off = 32; off; off >>= 1) m = fmaxf(m, __shfl_down(m, off));
        if (lane == 0) red[w] = m;
    }
    __syncthreads();
    m = fmaxf(fmaxf(red[0], red[1]), fmaxf(red[2], red[3]));
    if (t < NR) e = expf(logit[t] - m);
    if (t < 256) {
        float ss = e;
        for (int off = 32; off; off >>= 1) ss += __shfl_down(ss, off);
        if (lane == 0) red[4 + w] = ss;
    }
    __syncthreads();
    const float S = red[4] + red[5] + red[6] + red[7];
    if (t < NR) sc[t] = e / S;
    __syncthreads();

    // phase 3: apply. half = n-range split; 512 threads cover 1024 cols (2 each)
    const int half = t >> 9;
    const int c2 = (t & 511) * 2;
    float a0 = 0.f, a1 = 0.f;
    const int nbeg = half * (NR / 2), nend = nbeg + (NR / 2);
    if (VBF) {
        const ushort* vb = (const ushort*)visp + (size_t)b * NR * DV + c2;
        for (int n = nbeg; n < nend; ++n) {
            const float s = sc[n];
            const ushort2 v = *(const ushort2*)&vb[(size_t)n * DV];
            a0 = fmaf(s, bf2f(v.x), a0);
            a1 = fmaf(s, bf2f(v.y), a1);
        }
    } else {
        const float* vb = (const float*)visp + (size_t)b * NR * DV + c2;
        for (int n = nbeg; n < nend; ++n) {
            const float s = sc[n];
            const float2 v = *(const float2*)&vb[(size_t)n * DV];
            a0 = fmaf(s, v.x, a0);
            a1 = fmaf(s, v.y, a1);
        }
    }
    part[half][c2] = a0;
    part[half][c2 + 1] = a1;
    __syncthreads();
    att_out[(size_t)b * DV + t] = part[0][t] + part[1][t];
}

// ---------------------------------------------------------------------------
// LSTM pointwise, float4 per thread.
// ---------------------------------------------------------------------------
__global__ __launch_bounds__(256) void lstm_pw4(
    const float* __restrict__ gates, float* __restrict__ c, float* __restrict__ hnew)
{
    const int i4 = (blockIdx.x * 256 + threadIdx.x) * 4;
    const int b  = i4 >> 10;
    const int hh = i4 & 1023;
    const float* g = gates + (size_t)b * 4 * HH;
    const float4 gi = *(const float4*)&g[hh];
    const float4 gf = *(const float4*)&g[HH + hh];
    const float4 gg = *(const float4*)&g[2 * HH + hh];
    const float4 go = *(const float4*)&g[3 * HH + hh];
    float4 cv = *(float4*)&c[i4];
    float4 hv;
    cv.x = sigmoidf_(gf.x) * cv.x + sigmoidf_(gi.x) * tanhf(gg.x);
    cv.y = sigmoidf_(gf.y) * cv.y + sigmoidf_(gi.y) * tanhf(gg.y);
    cv.z = sigmoidf_(gf.z) * cv.z + sigmoidf_(gi.z) * tanhf(gg.z);
    cv.w = sigmoidf_(gf.w) * cv.w + sigmoidf_(gi.w) * tanhf(gg.w);
    hv.x = sigmoidf_(go.x) * tanhf(cv.x);
    hv.y = sigmoidf_(go.y) * tanhf(cv.y);
    hv.z = sigmoidf_(go.z) * tanhf(cv.z);
    hv.w = sigmoidf_(go.w) * tanhf(cv.w);
    *(float4*)&c[i4]    = cv;
    *(float4*)&hnew[i4] = hv;
}

// ---------------------------------------------------------------------------
// final stop projection: p[b,:] = pt[b,:] @ fw^T + fb (fw: [2, IS])
// ---------------------------------------------------------------------------
__global__ __launch_bounds__(256) void stop_final(
    const float* __restrict__ pt, const float* __restrict__ fw,
    const float* __restrict__ fb, float* __restrict__ outp)
{
    const int b = blockIdx.x;
    const int t = threadIdx.x;
    const int lane = t & 63;
    const int w = t >> 6;

    __shared__ float red[16];
    const float v = pt[b * IS + t];
    float p0 = v * fw[t];
    float p1 = v * fw[IS + t];
    for (int off = 32; off; off >>= 1) {
        p0 += __shfl_down(p0, off);
        p1 += __shfl_down(p1, off);
    }
    if (lane == 0) { red[w] = p0; red[8 + w] = p1; }
    __syncthreads();
    if (t == 0) {
        outp[(size_t)b * ST * 2 + 0] = red[0] + red[1] + red[2] + red[3] + fb[0];
        outp[(size_t)b * ST * 2 + 1] = red[8] + red[9] + red[10] + red[11] + fb[1];
    }
}

// ---------------------------------------------------------------------------
extern "C" void kernel_launch(void* const* d_in, const int* in_sizes, int n_in,
                              void* d_out, int out_size, void* d_ws, size_t ws_size,
                              hipStream_t stream)
{
    const float* vis        = (const float*)d_in[0];
    const float* enc_att_w  = (const float*)d_in[2];
    const float* enc_att_b  = (const float*)d_in[3];
    const float* dec_att_w  = (const float*)d_in[4];
    const float* dec_att_b  = (const float*)d_in[5];
    const float* full_att_w = (const float*)d_in[6];
    const float* full_att_b = (const float*)d_in[7];
    const float* ctx_w      = (const float*)d_in[8];
    const float* ctx_b      = (const float*)d_in[9];
    const float* W_ih       = (const float*)d_in[10];
    const float* b_ih       = (const float*)d_in[11];
    const float* W_hh       = (const float*)d_in[12];
    const float* b_hh       = (const float*)d_in[13];
    const float* topic_hid_w = (const float*)d_in[14];
    const float* topic_hid_b = (const float*)d_in[15];
    const float* topic_ctx_w = (const float*)d_in[16];
    const float* topic_ctx_b = (const float*)d_in[17];
    const float* stop_prev_w = (const float*)d_in[18];
    const float* stop_prev_b = (const float*)d_in[19];
    const float* stop_cur_w  = (const float*)d_in[20];
    const float* stop_cur_b  = (const float*)d_in[21];
    const float* final_stop_w = (const float*)d_in[22];
    const float* final_stop_b = (const float*)d_in[23];

    float* out_topics = (float*)d_out;                        // [B, ST, WI]
    float* out_ps     = (float*)d_out + (size_t)BB * ST * WI; // [B, ST, 2]

    char* ws = (char*)d_ws;
    size_t off = 0;
    auto alloc = [&](size_t bytes) -> void* {
        void* p = (void*)(ws + off);
        off += (bytes + 255) & ~(size_t)255;
        return p;
    };
    ushort* vis_att = (ushort*)alloc((size_t)BB * NR * AT * 2);  // 25.7 MB bf16
    const size_t WTOT = 12582912;
    ushort* wh = (ushort*)alloc(WTOT * 2);                       // 25.2 MB
    ushort* wl = (ushort*)alloc(WTOT * 2);                       // 25.2 MB
    float* hA      = (float*)alloc((size_t)BB * HH * 4);
    float* hB      = (float*)alloc((size_t)BB * HH * 4);
    float* cbuf    = (float*)alloc((size_t)BB * HH * 4);
    float* att_out = (float*)alloc((size_t)BB * DV * 4);
    float* decb    = (float*)alloc((size_t)BB * AT * 4);
    float* ctx     = (float*)alloc((size_t)BB * SI * 4);
    float* gates   = (float*)alloc((size_t)BB * 4 * HH * 4);
    float* pt      = (float*)alloc((size_t)BB * IS * 4);
    if (off > ws_size) return;  // core workspace too small — fail visibly
    // optional bf16 copy of vis (98 MB) — falls back to fp32 reads if no room
    ushort* vis_bf = nullptr;
    {
        const size_t need = (size_t)BB * NR * DV * 2;
        if (off + need <= ws_size) vis_bf = (ushort*)alloc(need);
    }

    // weight segment offsets (elements) within the pool
    const size_t O_ENC = 0;          // 256x1024
    const size_t O_DEC = 262144;     // 256x1024
    const size_t O_CTX = 524288;     // 1024x1024
    const size_t O_IH  = 1572864;    // 4096x1024
    const size_t O_HH  = 5767168;    // 4096x1024
    const size_t O_TH  = 9961472;    // 1024x1024
    const size_t O_TC  = 11010048;   // 1024x1024
    const size_t O_SP  = 12058624;   // 256x1024
    const size_t O_SC  = 12320768;   // 256x1024

    CvtTab tab;
    const float* srcs[9] = {enc_att_w, dec_att_w, ctx_w, W_ih, W_hh,
                            topic_hid_w, topic_ctx_w, stop_prev_w, stop_cur_w};
    const size_t offs[9] = {O_ENC, O_DEC, O_CTX, O_IH, O_HH, O_TH, O_TC, O_SP, O_SC};
    for (int i = 0; i < 9; ++i) {
        tab.s[i] = srcs[i];
        tab.h[i] = wh + offs[i];
        tab.l[i] = wl + offs[i];
    }

    hipMemsetAsync(hA, 0, (size_t)BB * HH * 4, stream);
    hipMemsetAsync(cbuf, 0, (size_t)BB * HH * 4, stream);

    convert_split<<<12288, 256, 0, stream>>>(tab);

    // hoisted encoder projection (+ bf16 vis side-product)
    if (vis_bf)
        mgemm_pre<1><<<(BB * NR) / 64, 256, 0, stream>>>(
            vis, wh + O_ENC, wl + O_ENC, enc_att_b, vis_att, vis_bf);
    else
        mgemm_pre<0><<<(BB * NR) / 64, 256, 0, stream>>>(
            vis, wh + O_ENC, wl + O_ENC, enc_att_b, vis_att, nullptr);

    float* hc = hA;   // h_prev
    float* hn = hB;   // h_new
    for (int s = 0; s < ST; ++s) {
        // dec = h @ dec_att_w^T + dec_att_b   (weights read once per step)
        mgemm<0, 0><<<dim3(AT / 64, BB / 64), 256, 0, stream>>>(
            hc, wh + O_DEC, wl + O_DEC, dec_att_b,
            nullptr, nullptr, nullptr, nullptr,
            decb, BB, AT, HH, AT);
        // fused logits + softmax + apply
        if (vis_bf)
            att_step<1><<<BB, 1024, 0, stream>>>(vis_att, decb, full_att_w, full_att_b,
                                                 vis_bf, att_out);
        else
            att_step<0><<<BB, 1024, 0, stream>>>(vis_att, decb, full_att_w, full_att_b,
                                                 vis, att_out);
        // ctx = att_out @ ctx_w^T + ctx_b
        mgemm<0, 0><<<dim3(SI / 64, BB / 64), 256, 0, stream>>>(
            att_out, wh + O_CTX, wl + O_CTX, ctx_b,
            nullptr, nullptr, nullptr, nullptr,
            ctx, BB, SI, DV, SI);
        // gates = ctx @ W_ih^T + b_ih + h @ W_hh^T + b_hh
        mgemm<0, 1><<<dim3(4 * HH / 64, BB / 64), 256, 0, stream>>>(
            ctx, wh + O_IH, wl + O_IH, b_ih,
            hc, wh + O_HH, wl + O_HH, b_hh,
            gates, BB, 4 * HH, SI, 4 * HH);
        lstm_pw4<<<(BB * HH) / 1024, 256, 0, stream>>>(gates, cbuf, hn);
        // topic -> out
        mgemm<1, 1><<<dim3(WI / 64, BB / 64), 256, 0, stream>>>(
            hn, wh + O_TH, wl + O_TH, topic_hid_b,
            ctx, wh + O_TC, wl + O_TC, topic_ctx_b,
            out_topics + (size_t)s * WI, BB, WI, HH, ST * WI);
        // stop inner
        mgemm<1, 1><<<dim3(IS / 64, BB / 64), 256, 0, stream>>>(
            hc, wh + O_SP, wl + O_SP, stop_prev_b,
            hn, wh + O_SC, wl + O_SC, stop_cur_b,
            pt, BB, IS, HH, IS);
        stop_final<<<BB, 256, 0, stream>>>(pt, final_stop_w, final_stop_b,
                                           out_ps + (size_t)s * 2);
        float* tmp = hc; hc = hn; hn = tmp;
    }
}

// Round 5
// 1618.137 us; speedup vs baseline: 4.0940x; 1.7571x over previous
//
#include <hip/hip_runtime.h>
#include <hip/hip_bf16.h>
#include <math.h>

// Problem constants (SentenceLSTM)
static constexpr int BB = 256;    // batch
static constexpr int NR = 196;    // regions
static constexpr int DV = 1024;   // vis embed dim
static constexpr int HH = 1024;   // hidden
static constexpr int AT = 256;    // att dim
static constexpr int SI = 1024;   // sem input dim (ctx)
static constexpr int WI = 1024;   // topic width
static constexpr int IS = 256;    // stop inner dim
static constexpr int ST = 10;     // sentence steps

__device__ __forceinline__ float sigmoidf_(float x) { return 1.0f / (1.0f + expf(-x)); }

// bf16 round-to-nearest-even, bit-level
__device__ __forceinline__ ushort f2bf(float x) {
    uint u = __float_as_uint(x);
    return (ushort)((u + 0x7FFFu + ((u >> 16) & 1u)) >> 16);
}
__device__ __forceinline__ float bf2f(ushort b) { return __uint_as_float(((uint)b) << 16); }

using bf16x8 = __attribute__((ext_vector_type(8))) short;
using f32x4  = __attribute__((ext_vector_type(4))) float;
#define MFMA_B16(a, b, c) __builtin_amdgcn_mfma_f32_16x16x32_bf16((a), (b), (c), 0, 0, 0)

// split 8 fp32 (two float4) into hi/lo bf16 packed as uint4 each
__device__ __forceinline__ void split8(const float4& u, const float4& v, uint4& hq, uint4& lq) {
    ushort h0 = f2bf(u.x), h1 = f2bf(u.y), h2 = f2bf(u.z), h3 = f2bf(u.w);
    ushort h4 = f2bf(v.x), h5 = f2bf(v.y), h6 = f2bf(v.z), h7 = f2bf(v.w);
    hq.x = h0 | ((uint)h1 << 16); hq.y = h2 | ((uint)h3 << 16);
    hq.z = h4 | ((uint)h5 << 16); hq.w = h6 | ((uint)h7 << 16);
    ushort l0 = f2bf(u.x - bf2f(h0)), l1 = f2bf(u.y - bf2f(h1));
    ushort l2 = f2bf(u.z - bf2f(h2)), l3 = f2bf(u.w - bf2f(h3));
    ushort l4 = f2bf(v.x - bf2f(h4)), l5 = f2bf(v.y - bf2f(h5));
    ushort l6 = f2bf(v.z - bf2f(h6)), l7 = f2bf(v.w - bf2f(h7));
    lq.x = l0 | ((uint)l1 << 16); lq.y = l2 | ((uint)l3 << 16);
    lq.z = l4 | ((uint)l5 << 16); lq.w = l6 | ((uint)l7 << 16);
}

// ---------------------------------------------------------------------------
// Weight fp32 -> (hi,lo) bf16 split conversion. Segments 3,4 (W_ih, W_hh)
// are row-interleaved: out row r' = (r&1023)*4 + (r>>10)  (col' = unit*4+gate)
// so the gates GEMM epilogue can do the LSTM pointwise locally.
// ---------------------------------------------------------------------------
struct CvtTab { const float* s[9]; ushort* h[9]; ushort* l[9]; };

__global__ __launch_bounds__(256) void convert_split(CvtTab tab) {
    const int cum[10] = {0, 256, 512, 1536, 5632, 9728, 10752, 11776, 12032, 12288};
    const int bid = blockIdx.x;
    int seg = 0;
#pragma unroll
    for (int i = 1; i < 9; ++i) if (bid >= cum[i]) seg = i;
    const float* s = tab.s[seg];
    ushort* h = tab.h[seg];
    ushort* l = tab.l[seg];
    const int r = bid - cum[seg];
    int rd = r;
    if (seg == 3 || seg == 4) rd = (r & 1023) * 4 + (r >> 10);
    const int src = r * 1024 + threadIdx.x * 4;
    const size_t dst = (size_t)rd * 1024 + threadIdx.x * 4;
    float4 v = *(const float4*)(s + src);
    ushort h0 = f2bf(v.x), h1 = f2bf(v.y), h2 = f2bf(v.z), h3 = f2bf(v.w);
    uint2 hq, lq;
    hq.x = h0 | ((uint)h1 << 16); hq.y = h2 | ((uint)h3 << 16);
    ushort l0 = f2bf(v.x - bf2f(h0)), l1 = f2bf(v.y - bf2f(h1));
    ushort l2 = f2bf(v.z - bf2f(h2)), l3 = f2bf(v.w - bf2f(h3));
    lq.x = l0 | ((uint)l1 << 16); lq.y = l2 | ((uint)l3 << 16);
    *(uint2*)(h + dst) = hq;
    *(uint2*)(l + dst) = lq;
}

// ---------------------------------------------------------------------------
// mgemm: act( A1*W1^T + b1 [+ A2*W2^T + b2] ) via split-bf16 MFMA.
// EPI: 0=store, 1=tanh+store, 2=LSTM pointwise (interleaved gate cols;
//       writes c in place and h_new; b1/b2 = b_ih/b_hh deinterleaved lookup).
// OMAP: 0: C[row*ldc+col]; 1: row=(s*BB+b) -> C[(b*ST+s)*ldc+col].
// ---------------------------------------------------------------------------
template <int EPI, int DUAL, int OMAP>
__global__ __launch_bounds__(256) void mgemm(
    const float* __restrict__ A1, const ushort* __restrict__ W1h, const ushort* __restrict__ W1l,
    const float* __restrict__ b1,
    const float* __restrict__ A2, const ushort* __restrict__ W2h, const ushort* __restrict__ W2l,
    const float* __restrict__ b2,
    float* __restrict__ C, int M, int N, int K, int ldc,
    float* __restrict__ cvec, float* __restrict__ hnew)
{
    __shared__ __align__(16) ushort SM[4 * 64 * 40];   // 20 KB
    ushort* Ah = SM; ushort* Al = SM + 2560; ushort* Bh = SM + 5120; ushort* Bl = SM + 7680;

    const int t = threadIdx.x;
    const int m0 = blockIdx.y * 64, n0 = blockIdx.x * 64;
    const int w = t >> 6, lane = t & 63;
    const int l15 = lane & 15, q = lane >> 4;
    const int sr = t >> 2, sq = (t & 3) * 8;
    const int KC = K >> 5, nch = (DUAL ? 2 : 1) * KC;

    f32x4 acc[4] = {};
    float4 pa0, pa1; uint4 pbh, pbl;

    auto pref = [&](int c) {
        const int pass = DUAL ? (c >= KC ? 1 : 0) : 0;
        const int k0 = (c - pass * KC) << 5;
        const float* A = pass ? A2 : A1;
        const ushort* Wh = pass ? W2h : W1h;
        const ushort* Wl = pass ? W2l : W1l;
        const float* ap = &A[(size_t)(m0 + sr) * K + k0 + sq];
        pa0 = *(const float4*)ap;
        pa1 = *(const float4*)(ap + 4);
        pbh = *(const uint4*)&Wh[(size_t)(n0 + sr) * K + k0 + sq];
        pbl = *(const uint4*)&Wl[(size_t)(n0 + sr) * K + k0 + sq];
    };
    pref(0);

    for (int c = 0; c < nch; ++c) {
        __syncthreads();
        uint4 hq, lq; split8(pa0, pa1, hq, lq);
        *(uint4*)&Ah[sr * 40 + sq] = hq;
        *(uint4*)&Al[sr * 40 + sq] = lq;
        *(uint4*)&Bh[sr * 40 + sq] = pbh;
        *(uint4*)&Bl[sr * 40 + sq] = pbl;
        __syncthreads();
        if (c + 1 < nch) pref(c + 1);
        const bf16x8 bh = *(const bf16x8*)&Bh[(w * 16 + l15) * 40 + q * 8];
        const bf16x8 bl = *(const bf16x8*)&Bl[(w * 16 + l15) * 40 + q * 8];
#pragma unroll
        for (int mi = 0; mi < 4; ++mi) {
            const bf16x8 ah = *(const bf16x8*)&Ah[(mi * 16 + l15) * 40 + q * 8];
            const bf16x8 al = *(const bf16x8*)&Al[(mi * 16 + l15) * 40 + q * 8];
            acc[mi] = MFMA_B16(ah, bh, acc[mi]);
            acc[mi] = MFMA_B16(ah, bl, acc[mi]);
            acc[mi] = MFMA_B16(al, bh, acc[mi]);
        }
    }

    if (EPI == 2) {
        // LSTM epilogue: gates cols are interleaved (col' = unit*4 + gate).
        __syncthreads();                       // staging LDS reads done
        float* G = (float*)SM;                 // 64x68 fp32 = 17.4 KB
        const int colL = w * 16 + l15;
        const int colG = n0 + colL;
        const int gate = colG & 3, unit = colG >> 2;
        const float bias = b1[gate * 1024 + unit] + b2[gate * 1024 + unit];
#pragma unroll
        for (int mi = 0; mi < 4; ++mi)
#pragma unroll
            for (int j = 0; j < 4; ++j)
                G[(mi * 16 + q * 4 + j) * 68 + colL] = acc[mi][j] + bias;
        __syncthreads();
        const int u0 = n0 >> 2;
#pragma unroll
        for (int p = t; p < 1024; p += 256) {
            const int row = p >> 4, ul = p & 15;
            const float4 g4 = *(const float4*)&G[row * 68 + ul * 4];  // i,f,g,o
            const size_t ci = (size_t)(m0 + row) * HH + u0 + ul;
            const float cn = sigmoidf_(g4.y) * cvec[ci] + sigmoidf_(g4.x) * tanhf(g4.z);
            cvec[ci] = cn;
            hnew[ci] = sigmoidf_(g4.w) * tanhf(cn);
        }
        return;
    }

    const int col = n0 + w * 16 + l15;
    float bias = b1[col];
    if (DUAL) bias += b2[col];
#pragma unroll
    for (int mi = 0; mi < 4; ++mi) {
#pragma unroll
        for (int j = 0; j < 4; ++j) {
            const int row = m0 + mi * 16 + q * 4 + j;
            float v = acc[mi][j] + bias;
            if (EPI == 1) v = tanhf(v);
            if (OMAP)
                C[((size_t)(row & 255) * ST + (row >> 8)) * ldc + col] = v;
            else
                C[(size_t)row * ldc + col] = v;
        }
    }
}

// ---------------------------------------------------------------------------
// mgemm_pre: vis_att(bf16) = vis @ enc_att_w^T + b; optionally emits
// vis_bf = bf16(vis) as staging side-product. Tile 64x256.
// ---------------------------------------------------------------------------
template <int WRITE_VBF>
__global__ __launch_bounds__(256) void mgemm_pre(
    const float* __restrict__ A, const ushort* __restrict__ Wh, const ushort* __restrict__ Wl,
    const float* __restrict__ bias, ushort* __restrict__ C, ushort* __restrict__ vbf)
{
    __shared__ __align__(16) ushort Ah[64 * 40], Al[64 * 40];
    __shared__ __align__(16) ushort Bh[256 * 40], Bl[256 * 40];

    const int t = threadIdx.x;
    const int m0 = blockIdx.x * 64;
    const int w = t >> 6, lane = t & 63;
    const int l15 = lane & 15, q = lane >> 4;
    const int sr = t >> 2, sq = (t & 3) * 8;
    const int K = DV;

    f32x4 acc[4][4] = {};
    float4 pa0, pa1;
    auto prefA = [&](int k0) {
        const float* ap = &A[(size_t)(m0 + sr) * K + k0 + sq];
        pa0 = *(const float4*)ap;
        pa1 = *(const float4*)(ap + 4);
    };
    prefA(0);

    for (int c = 0; c < 32; ++c) {
        const int k0 = c << 5;
        __syncthreads();
        uint4 hq, lq; split8(pa0, pa1, hq, lq);
        *(uint4*)&Ah[sr * 40 + sq] = hq;
        *(uint4*)&Al[sr * 40 + sq] = lq;
        if (WRITE_VBF)
            *(uint4*)&vbf[(size_t)(m0 + sr) * K + k0 + sq] = hq;
#pragma unroll
        for (int i = 0; i < 4; ++i) {
            const int r = sr + 64 * i;
            *(uint4*)&Bh[r * 40 + sq] = *(const uint4*)&Wh[(size_t)r * K + k0 + sq];
            *(uint4*)&Bl[r * 40 + sq] = *(const uint4*)&Wl[(size_t)r * K + k0 + sq];
        }
        __syncthreads();
        if (c + 1 < 32) prefA((c + 1) << 5);

        bf16x8 ah[4], al[4];
#pragma unroll
        for (int mi = 0; mi < 4; ++mi) {
            ah[mi] = *(const bf16x8*)&Ah[(mi * 16 + l15) * 40 + q * 8];
            al[mi] = *(const bf16x8*)&Al[(mi * 16 + l15) * 40 + q * 8];
        }
#pragma unroll
        for (int ni = 0; ni < 4; ++ni) {
            const bf16x8 bh = *(const bf16x8*)&Bh[(w * 64 + ni * 16 + l15) * 40 + q * 8];
            const bf16x8 bl = *(const bf16x8*)&Bl[(w * 64 + ni * 16 + l15) * 40 + q * 8];
#pragma unroll
            for (int mi = 0; mi < 4; ++mi) {
                acc[mi][ni] = MFMA_B16(ah[mi], bh, acc[mi][ni]);
                acc[mi][ni] = MFMA_B16(ah[mi], bl, acc[mi][ni]);
                acc[mi][ni] = MFMA_B16(al[mi], bh, acc[mi][ni]);
            }
        }
    }

#pragma unroll
    for (int ni = 0; ni < 4; ++ni) {
        const int col = w * 64 + ni * 16 + l15;
        const float bb = bias[col];
#pragma unroll
        for (int mi = 0; mi < 4; ++mi)
#pragma unroll
            for (int j = 0; j < 4; ++j) {
                const int row = m0 + mi * 16 + q * 4 + j;
                C[(size_t)row * AT + col] = f2bf(acc[mi][ni][j] + bb);
            }
    }
}

// ---------------------------------------------------------------------------
// att_step: per batch row b (one 1024-thread block):
//   phase 0: dec[a] = h[b] . dec_att_w[a] + b_dec          (fp32, exact)
//   phase 1: logit[n] = sum_a tanh(vis_att+dec)*fw + fb
//   phase 2: softmax; phase 3: att_out = sc . vis
// ---------------------------------------------------------------------------
template <int VBF>
__global__ __launch_bounds__(1024) void att_step(
    const ushort* __restrict__ vis_att, const float* __restrict__ h,
    const float* __restrict__ dec_w, const float* __restrict__ dec_b,
    const float* __restrict__ fw, const float* __restrict__ fbp,
    const void* __restrict__ visp, float* __restrict__ att_out)
{
    const int b = blockIdx.x;
    const int t = threadIdx.x;
    const int lane = t & 63;
    const int w = t >> 6;

    __shared__ float hs[HH];
    __shared__ float decs[AT];
    __shared__ float fwv[AT];
    __shared__ float logit[NR + 4];
    __shared__ float sc[NR + 4];
    __shared__ float red[8];
    __shared__ float part[2][DV];

    hs[t] = h[(size_t)b * HH + t];
    if (t < AT) fwv[t] = fw[t];
    __syncthreads();
    const float fb = fbp[0];

    // phase 0: dec — wave w computes outputs a = w*16 .. +15
#pragma unroll
    for (int j = 0; j < 16; ++j) {
        const int a = w * 16 + j;
        const float* wr = dec_w + (size_t)a * HH;
        float p = 0.f;
#pragma unroll
        for (int i = 0; i < 4; ++i) {
            const float4 wv = *(const float4*)&wr[i * 256 + lane * 4];
            const float4 hv = *(const float4*)&hs[i * 256 + lane * 4];
            p = fmaf(wv.x, hv.x, p); p = fmaf(wv.y, hv.y, p);
            p = fmaf(wv.z, hv.z, p); p = fmaf(wv.w, hv.w, p);
        }
        for (int off = 32; off; off >>= 1) p += __shfl_down(p, off);
        if (lane == 0) decs[a] = p + dec_b[a];
    }
    __syncthreads();

    // phase 1: logits — wave w handles rows n = w, w+16, ...
    for (int n = w; n < NR; n += 16) {
        const ushort4 v4 = *(const ushort4*)&vis_att[((size_t)b * NR + n) * AT + lane * 4];
        const int a = lane * 4;
        float s = tanhf(bf2f(v4.x) + decs[a]) * fwv[a];
        s = fmaf(tanhf(bf2f(v4.y) + decs[a + 1]), fwv[a + 1], s);
        s = fmaf(tanhf(bf2f(v4.z) + decs[a + 2]), fwv[a + 2], s);
        s = fmaf(tanhf(bf2f(v4.w) + decs[a + 3]), fwv[a + 3], s);
        for (int off = 32; off; off >>= 1) s += __shfl_down(s, off);
        if (lane == 0) logit[n] = s + fb;
    }
    __syncthreads();

    // phase 2: softmax (first 4 waves)
    float m = -1e30f, e = 0.f;
    if (t < NR) m = logit[t];
    if (t < 256) {
        for (int off = 32; off; off >>= 1) m = fmaxf(m, __shfl_down(m, off));
        if (lane == 0) red[w] = m;
    }
    __syncthreads();
    m = fmaxf(fmaxf(red[0], red[1]), fmaxf(red[2], red[3]));
    if (t < NR) e = expf(logit[t] - m);
    if (t < 256) {
        float ss = e;
        for (int off = 32; off; off >>= 1) ss += __shfl_down(ss, off);
        if (lane == 0) red[4 + w] = ss;
    }
    __syncthreads();
    const float S = red[4] + red[5] + red[6] + red[7];
    if (t < NR) sc[t] = e / S;
    __syncthreads();

    // phase 3: apply. n-range split in half; 512 threads cover 1024 cols
    const int half = t >> 9;
    const int c2 = (t & 511) * 2;
    float a0 = 0.f, a1 = 0.f;
    const int nbeg = half * (NR / 2), nend = nbeg + (NR / 2);
    if (VBF) {
        const ushort* vb = (const ushort*)visp + (size_t)b * NR * DV + c2;
        for (int n = nbeg; n < nend; ++n) {
            const float s = sc[n];
            const ushort2 v = *(const ushort2*)&vb[(size_t)n * DV];
            a0 = fmaf(s, bf2f(v.x), a0);
            a1 = fmaf(s, bf2f(v.y), a1);
        }
    } else {
        const float* vb = (const float*)visp + (size_t)b * NR * DV + c2;
        for (int n = nbeg; n < nend; ++n) {
            const float s = sc[n];
            const float2 v = *(const float2*)&vb[(size_t)n * DV];
            a0 = fmaf(s, v.x, a0);
            a1 = fmaf(s, v.y, a1);
        }
    }
    part[half][c2] = a0;
    part[half][c2 + 1] = a1;
    __syncthreads();
    att_out[(size_t)b * DV + t] = part[0][t] + part[1][t];
}

// ---------------------------------------------------------------------------
// batched final stop projection over all (s,b): row = s*BB + b.
// ---------------------------------------------------------------------------
__global__ __launch_bounds__(256) void stop_final_all(
    const float* __restrict__ pt, const float* __restrict__ fw,
    const float* __restrict__ fb, float* __restrict__ outp)
{
    const int row = blockIdx.x;          // s*BB + b
    const int s = row >> 8, b = row & 255;
    const int t = threadIdx.x;
    const int lane = t & 63;
    const int w = t >> 6;

    __shared__ float red[16];
    const float v = pt[(size_t)row * IS + t];
    float p0 = v * fw[t];
    float p1 = v * fw[IS + t];
    for (int off = 32; off; off >>= 1) {
        p0 += __shfl_down(p0, off);
        p1 += __shfl_down(p1, off);
    }
    if (lane == 0) { red[w] = p0; red[8 + w] = p1; }
    __syncthreads();
    if (t == 0) {
        outp[((size_t)b * ST + s) * 2 + 0] = red[0] + red[1] + red[2] + red[3] + fb[0];
        outp[((size_t)b * ST + s) * 2 + 1] = red[8] + red[9] + red[10] + red[11] + fb[1];
    }
}

// ---------------------------------------------------------------------------
extern "C" void kernel_launch(void* const* d_in, const int* in_sizes, int n_in,
                              void* d_out, int out_size, void* d_ws, size_t ws_size,
                              hipStream_t stream)
{
    const float* vis        = (const float*)d_in[0];
    const float* enc_att_w  = (const float*)d_in[2];
    const float* enc_att_b  = (const float*)d_in[3];
    const float* dec_att_w  = (const float*)d_in[4];
    const float* dec_att_b  = (const float*)d_in[5];
    const float* full_att_w = (const float*)d_in[6];
    const float* full_att_b = (const float*)d_in[7];
    const float* ctx_w      = (const float*)d_in[8];
    const float* ctx_b      = (const float*)d_in[9];
    const float* W_ih       = (const float*)d_in[10];
    const float* b_ih       = (const float*)d_in[11];
    const float* W_hh       = (const float*)d_in[12];
    const float* b_hh       = (const float*)d_in[13];
    const float* topic_hid_w = (const float*)d_in[14];
    const float* topic_hid_b = (const float*)d_in[15];
    const float* topic_ctx_w = (const float*)d_in[16];
    const float* topic_ctx_b = (const float*)d_in[17];
    const float* stop_prev_w = (const float*)d_in[18];
    const float* stop_prev_b = (const float*)d_in[19];
    const float* stop_cur_w  = (const float*)d_in[20];
    const float* stop_cur_b  = (const float*)d_in[21];
    const float* final_stop_w = (const float*)d_in[22];
    const float* final_stop_b = (const float*)d_in[23];

    float* out_topics = (float*)d_out;                        // [B, ST, WI]
    float* out_ps     = (float*)d_out + (size_t)BB * ST * WI; // [B, ST, 2]

    char* ws = (char*)d_ws;
    size_t off = 0;
    auto alloc = [&](size_t bytes) -> void* {
        void* p = (void*)(ws + off);
        off += (bytes + 255) & ~(size_t)255;
        return p;
    };
    ushort* vis_att = (ushort*)alloc((size_t)BB * NR * AT * 2);      // 25.7 MB
    const size_t WTOT = 12582912;
    ushort* wh = (ushort*)alloc(WTOT * 2);                           // 25.2 MB
    ushort* wl = (ushort*)alloc(WTOT * 2);                           // 25.2 MB
    float* h_all   = (float*)alloc((size_t)(ST + 1) * BB * HH * 4);  // 11.5 MB
    float* ctx_all = (float*)alloc((size_t)ST * BB * SI * 4);        // 10.5 MB
    float* cbuf    = (float*)alloc((size_t)BB * HH * 4);
    float* att_out = (float*)alloc((size_t)BB * DV * 4);
    float* pt_all  = (float*)alloc((size_t)ST * BB * IS * 4);        // 2.6 MB
    if (off > ws_size) return;  // core workspace too small — fail visibly
    // optional bf16 copy of vis (98 MB) — falls back to fp32 reads if no room
    ushort* vis_bf = nullptr;
    {
        const size_t need = (size_t)BB * NR * DV * 2;
        if (off + need <= ws_size) vis_bf = (ushort*)alloc(need);
    }

    // weight segment offsets (elements) within the pool
    const size_t O_ENC = 0;          // 256x1024
    const size_t O_DEC = 262144;     // 256x1024 (unused in GEMMs; dec is fused fp32)
    const size_t O_CTX = 524288;     // 1024x1024
    const size_t O_IH  = 1572864;    // 4096x1024 (row-interleaved)
    const size_t O_HH  = 5767168;    // 4096x1024 (row-interleaved)
    const size_t O_TH  = 9961472;    // 1024x1024
    const size_t O_TC  = 11010048;   // 1024x1024
    const size_t O_SP  = 12058624;   // 256x1024
    const size_t O_SC  = 12320768;   // 256x1024

    CvtTab tab;
    const float* srcs[9] = {enc_att_w, dec_att_w, ctx_w, W_ih, W_hh,
                            topic_hid_w, topic_ctx_w, stop_prev_w, stop_cur_w};
    const size_t offs[9] = {O_ENC, O_DEC, O_CTX, O_IH, O_HH, O_TH, O_TC, O_SP, O_SC};
    for (int i = 0; i < 9; ++i) {
        tab.s[i] = srcs[i];
        tab.h[i] = wh + offs[i];
        tab.l[i] = wl + offs[i];
    }

    hipMemsetAsync(h_all, 0, (size_t)BB * HH * 4, stream);   // h_0 = 0
    hipMemsetAsync(cbuf, 0, (size_t)BB * HH * 4, stream);    // c_0 = 0

    convert_split<<<12288, 256, 0, stream>>>(tab);

    // hoisted encoder projection (+ bf16 vis side-product)
    if (vis_bf)
        mgemm_pre<1><<<(BB * NR) / 64, 256, 0, stream>>>(
            vis, wh + O_ENC, wl + O_ENC, enc_att_b, vis_att, vis_bf);
    else
        mgemm_pre<0><<<(BB * NR) / 64, 256, 0, stream>>>(
            vis, wh + O_ENC, wl + O_ENC, enc_att_b, vis_att, nullptr);

    for (int s = 0; s < ST; ++s) {
        float* hc = h_all + (size_t)s * BB * HH;
        float* hn = h_all + (size_t)(s + 1) * BB * HH;
        float* ctxs = ctx_all + (size_t)s * BB * SI;
        // fused dec + logits + softmax + apply
        if (vis_bf)
            att_step<1><<<BB, 1024, 0, stream>>>(vis_att, hc, dec_att_w, dec_att_b,
                                                 full_att_w, full_att_b, vis_bf, att_out);
        else
            att_step<0><<<BB, 1024, 0, stream>>>(vis_att, hc, dec_att_w, dec_att_b,
                                                 full_att_w, full_att_b, vis, att_out);
        // ctx = att_out @ ctx_w^T + ctx_b
        mgemm<0, 0, 0><<<dim3(SI / 64, BB / 64), 256, 0, stream>>>(
            att_out, wh + O_CTX, wl + O_CTX, ctx_b,
            nullptr, nullptr, nullptr, nullptr,
            ctxs, BB, SI, DV, SI, nullptr, nullptr);
        // gates (interleaved) + fused LSTM pointwise -> cbuf, hn
        mgemm<2, 1, 0><<<dim3(4 * HH / 64, BB / 64), 256, 0, stream>>>(
            ctxs, wh + O_IH, wl + O_IH, b_ih,
            hc, wh + O_HH, wl + O_HH, b_hh,
            nullptr, BB, 4 * HH, SI, 0, cbuf, hn);
    }

    // deferred batched heads over all steps (rows = s*BB + b)
    // topic = tanh(h_new @ th^T + ctx @ tc^T + biases) -> out (row remap)
    mgemm<1, 1, 1><<<dim3(WI / 64, (ST * BB) / 64), 256, 0, stream>>>(
        h_all + (size_t)BB * HH, wh + O_TH, wl + O_TH, topic_hid_b,
        ctx_all, wh + O_TC, wl + O_TC, topic_ctx_b,
        out_topics, ST * BB, WI, HH, WI, nullptr, nullptr);
    // stop inner = tanh(h_prev @ sp^T + h_new @ sc^T + biases)
    mgemm<1, 1, 0><<<dim3(IS / 64, (ST * BB) / 64), 256, 0, stream>>>(
        h_all, wh + O_SP, wl + O_SP, stop_prev_b,
        h_all + (size_t)BB * HH, wh + O_SC, wl + O_SC, stop_cur_b,
        pt_all, ST * BB, IS, HH, IS, nullptr, nullptr);
    stop_final_all<<<ST * BB, 256, 0, stream>>>(pt_all, final_stop_w, final_stop_b, out_ps);
}

// Round 6
// 1280.702 us; speedup vs baseline: 5.1726x; 1.2635x over previous
//
#include <hip/hip_runtime.h>
#include <hip/hip_bf16.h>
#include <math.h>

// Problem constants (SentenceLSTM)
static constexpr int BB = 256;    // batch
static constexpr int NR = 196;    // regions
static constexpr int DV = 1024;   // vis embed dim
static constexpr int HH = 1024;   // hidden
static constexpr int AT = 256;    // att dim
static constexpr int SI = 1024;   // sem input dim (ctx)
static constexpr int WI = 1024;   // topic width
static constexpr int IS = 256;    // stop inner dim
static constexpr int ST = 10;     // sentence steps

__device__ __forceinline__ float sigmoidf_(float x) { return 1.0f / (1.0f + expf(-x)); }

// bf16 round-to-nearest-even, bit-level
__device__ __forceinline__ ushort f2bf(float x) {
    uint u = __float_as_uint(x);
    return (ushort)((u + 0x7FFFu + ((u >> 16) & 1u)) >> 16);
}
__device__ __forceinline__ float bf2f(ushort b) { return __uint_as_float(((uint)b) << 16); }

using bf16x8 = __attribute__((ext_vector_type(8))) short;
using f32x4  = __attribute__((ext_vector_type(4))) float;
#define MFMA_B16(a, b, c) __builtin_amdgcn_mfma_f32_16x16x32_bf16((a), (b), (c), 0, 0, 0)

// split 8 fp32 (two float4) into hi/lo bf16 packed as uint4 each
__device__ __forceinline__ void split8(const float4& u, const float4& v, uint4& hq, uint4& lq) {
    ushort h0 = f2bf(u.x), h1 = f2bf(u.y), h2 = f2bf(u.z), h3 = f2bf(u.w);
    ushort h4 = f2bf(v.x), h5 = f2bf(v.y), h6 = f2bf(v.z), h7 = f2bf(v.w);
    hq.x = h0 | ((uint)h1 << 16); hq.y = h2 | ((uint)h3 << 16);
    hq.z = h4 | ((uint)h5 << 16); hq.w = h6 | ((uint)h7 << 16);
    ushort l0 = f2bf(u.x - bf2f(h0)), l1 = f2bf(u.y - bf2f(h1));
    ushort l2 = f2bf(u.z - bf2f(h2)), l3 = f2bf(u.w - bf2f(h3));
    ushort l4 = f2bf(v.x - bf2f(h4)), l5 = f2bf(v.y - bf2f(h5));
    ushort l6 = f2bf(v.z - bf2f(h6)), l7 = f2bf(v.w - bf2f(h7));
    lq.x = l0 | ((uint)l1 << 16); lq.y = l2 | ((uint)l3 << 16);
    lq.z = l4 | ((uint)l5 << 16); lq.w = l6 | ((uint)l7 << 16);
}

// ---------------------------------------------------------------------------
// Weight fp32 -> (hi,lo) bf16 split conversion. Segments 3,4 (W_ih, W_hh)
// are row-interleaved: out row r' = (r&1023)*4 + (r>>10)  (col' = unit*4+gate).
// ---------------------------------------------------------------------------
struct CvtTab { const float* s[9]; ushort* h[9]; ushort* l[9]; };

__global__ __launch_bounds__(256) void convert_split(CvtTab tab) {
    const int cum[10] = {0, 256, 512, 1536, 5632, 9728, 10752, 11776, 12032, 12288};
    const int bid = blockIdx.x;
    int seg = 0;
#pragma unroll
    for (int i = 1; i < 9; ++i) if (bid >= cum[i]) seg = i;
    const float* s = tab.s[seg];
    ushort* h = tab.h[seg];
    ushort* l = tab.l[seg];
    const int r = bid - cum[seg];
    int rd = r;
    if (seg == 3 || seg == 4) rd = (r & 1023) * 4 + (r >> 10);
    const int src = r * 1024 + threadIdx.x * 4;
    const size_t dst = (size_t)rd * 1024 + threadIdx.x * 4;
    float4 v = *(const float4*)(s + src);
    ushort h0 = f2bf(v.x), h1 = f2bf(v.y), h2 = f2bf(v.z), h3 = f2bf(v.w);
    uint2 hq, lq;
    hq.x = h0 | ((uint)h1 << 16); hq.y = h2 | ((uint)h3 << 16);
    ushort l0 = f2bf(v.x - bf2f(h0)), l1 = f2bf(v.y - bf2f(h1));
    ushort l2 = f2bf(v.z - bf2f(h2)), l3 = f2bf(v.w - bf2f(h3));
    lq.x = l0 | ((uint)l1 << 16); lq.y = l2 | ((uint)l3 << 16);
    *(uint2*)(h + dst) = hq;
    *(uint2*)(l + dst) = lq;
}

// ---------------------------------------------------------------------------
// mgemm: act( A1*W1^T + b1 [+ A2*W2^T + b2] ) — 256-thr 64x64 kernel used for
// the large deferred head GEMMs (M=2560). EPI: 1=tanh+store, 0=store.
// OMAP: 1: row=(s*BB+b) -> C[(b*ST+s)*ldc+col].
// ---------------------------------------------------------------------------
template <int EPI, int DUAL, int OMAP>
__global__ __launch_bounds__(256) void mgemm(
    const float* __restrict__ A1, const ushort* __restrict__ W1h, const ushort* __restrict__ W1l,
    const float* __restrict__ b1,
    const float* __restrict__ A2, const ushort* __restrict__ W2h, const ushort* __restrict__ W2l,
    const float* __restrict__ b2,
    float* __restrict__ C, int M, int N, int K, int ldc)
{
    __shared__ __align__(16) ushort SM[4 * 64 * 40];   // 20 KB
    ushort* Ah = SM; ushort* Al = SM + 2560; ushort* Bh = SM + 5120; ushort* Bl = SM + 7680;

    const int t = threadIdx.x;
    const int m0 = blockIdx.y * 64, n0 = blockIdx.x * 64;
    const int w = t >> 6, lane = t & 63;
    const int l15 = lane & 15, q = lane >> 4;
    const int sr = t >> 2, sq = (t & 3) * 8;
    const int KC = K >> 5, nch = (DUAL ? 2 : 1) * KC;

    f32x4 acc[4] = {};
    float4 pa0, pa1; uint4 pbh, pbl;

    auto pref = [&](int c) {
        const int pass = DUAL ? (c >= KC ? 1 : 0) : 0;
        const int k0 = (c - pass * KC) << 5;
        const float* A = pass ? A2 : A1;
        const ushort* Wh = pass ? W2h : W1h;
        const ushort* Wl = pass ? W2l : W1l;
        const float* ap = &A[(size_t)(m0 + sr) * K + k0 + sq];
        pa0 = *(const float4*)ap;
        pa1 = *(const float4*)(ap + 4);
        pbh = *(const uint4*)&Wh[(size_t)(n0 + sr) * K + k0 + sq];
        pbl = *(const uint4*)&Wl[(size_t)(n0 + sr) * K + k0 + sq];
    };
    pref(0);

    for (int c = 0; c < nch; ++c) {
        __syncthreads();
        uint4 hq, lq; split8(pa0, pa1, hq, lq);
        *(uint4*)&Ah[sr * 40 + sq] = hq;
        *(uint4*)&Al[sr * 40 + sq] = lq;
        *(uint4*)&Bh[sr * 40 + sq] = pbh;
        *(uint4*)&Bl[sr * 40 + sq] = pbl;
        __syncthreads();
        if (c + 1 < nch) pref(c + 1);
        const bf16x8 bh = *(const bf16x8*)&Bh[(w * 16 + l15) * 40 + q * 8];
        const bf16x8 bl = *(const bf16x8*)&Bl[(w * 16 + l15) * 40 + q * 8];
#pragma unroll
        for (int mi = 0; mi < 4; ++mi) {
            const bf16x8 ah = *(const bf16x8*)&Ah[(mi * 16 + l15) * 40 + q * 8];
            const bf16x8 al = *(const bf16x8*)&Al[(mi * 16 + l15) * 40 + q * 8];
            acc[mi] = MFMA_B16(ah, bh, acc[mi]);
            acc[mi] = MFMA_B16(ah, bl, acc[mi]);
            acc[mi] = MFMA_B16(al, bh, acc[mi]);
        }
    }

    const int col = n0 + w * 16 + l15;
    float bias = b1[col];
    if (DUAL) bias += b2[col];
#pragma unroll
    for (int mi = 0; mi < 4; ++mi) {
#pragma unroll
        for (int j = 0; j < 4; ++j) {
            const int row = m0 + mi * 16 + q * 4 + j;
            float v = acc[mi][j] + bias;
            if (EPI == 1) v = tanhf(v);
            if (OMAP)
                C[((size_t)(row & 255) * ST + (row >> 8)) * ldc + col] = v;
            else
                C[(size_t)row * ldc + col] = v;
        }
    }
}

// ---------------------------------------------------------------------------
// mgemm8: 512-thread step GEMM, tile 64M x 32N. Two 4-wave groups split the
// reduction: DUAL=1 -> group g computes pass g (A1*W1 / A2*W2); DUAL=0 ->
// group g computes K-half g. Partial sums combined through LDS.
// EPI: 0 = store C + bias; 2 = fused LSTM pointwise (interleaved gate cols).
// ---------------------------------------------------------------------------
template <int EPI, int DUAL>
__global__ __launch_bounds__(512) void mgemm8(
    const float* __restrict__ A1, const ushort* __restrict__ W1h, const ushort* __restrict__ W1l,
    const float* __restrict__ b1,
    const float* __restrict__ A2, const ushort* __restrict__ W2h, const ushort* __restrict__ W2l,
    const float* __restrict__ b2,
    float* __restrict__ C, int K, int ldc,
    float* __restrict__ cvec, float* __restrict__ hnew)
{
    __shared__ __align__(16) ushort SM[20480];   // 40 KB

    const int t = threadIdx.x;
    const int m0 = blockIdx.y * 64, n0 = blockIdx.x * 32;
    const int w = t >> 6, lane = t & 63;
    const int g = w >> 2, wg = w & 3;
    const int l15 = lane & 15, q = lane >> 4;
    const int tl = t & 255;
    const int sr = tl >> 2, sq = (tl & 3) * 8;   // A staging (64 rows x 32k)
    const int br = tl >> 3, bq = (tl & 7) * 4;   // B staging (32 rows x 32k)
    const int mh = wg >> 1;                      // row half (rows mh*32..+31)
    const int colL = (wg & 1) * 16 + l15;        // 0..31

    ushort* Ah = SM + g * 7680;
    ushort* Al = Ah + 2560;
    ushort* Bh = Al + 2560;
    ushort* Bl = Bh + 1280;

    const int nchg = DUAL ? (K >> 5) : (K >> 6);
    const float*  A  = (DUAL && g) ? A2 : A1;
    const ushort* Wh = (DUAL && g) ? W2h : W1h;
    const ushort* Wl = (DUAL && g) ? W2l : W1l;
    const int kbase = DUAL ? 0 : g * (K >> 1);

    f32x4 acc[2] = {};
    float4 pa0, pa1; uint2 pbh, pbl;
    auto pref = [&](int c) {
        const int k0 = kbase + (c << 5);
        const float* ap = &A[(size_t)(m0 + sr) * K + k0 + sq];
        pa0 = *(const float4*)ap;
        pa1 = *(const float4*)(ap + 4);
        pbh = *(const uint2*)&Wh[(size_t)(n0 + br) * K + k0 + bq];
        pbl = *(const uint2*)&Wl[(size_t)(n0 + br) * K + k0 + bq];
    };
    pref(0);

    for (int c = 0; c < nchg; ++c) {
        __syncthreads();
        uint4 hq, lq; split8(pa0, pa1, hq, lq);
        *(uint4*)&Ah[sr * 40 + sq] = hq;
        *(uint4*)&Al[sr * 40 + sq] = lq;
        *(uint2*)&Bh[br * 40 + bq] = pbh;
        *(uint2*)&Bl[br * 40 + bq] = pbl;
        __syncthreads();
        if (c + 1 < nchg) pref(c + 1);
        const bf16x8 bh = *(const bf16x8*)&Bh[colL * 40 + q * 8];
        const bf16x8 bl = *(const bf16x8*)&Bl[colL * 40 + q * 8];
#pragma unroll
        for (int i = 0; i < 2; ++i) {
            const int mi = mh * 2 + i;
            const bf16x8 ah = *(const bf16x8*)&Ah[(mi * 16 + l15) * 40 + q * 8];
            const bf16x8 al = *(const bf16x8*)&Al[(mi * 16 + l15) * 40 + q * 8];
            acc[i] = MFMA_B16(ah, bh, acc[i]);
            acc[i] = MFMA_B16(ah, bl, acc[i]);
            acc[i] = MFMA_B16(al, bh, acc[i]);
        }
    }

    // combine group-1 partials into group-0 (stride 9 -> conflict-free)
    float* comb = (float*)(SM + 15360);   // byte 30720, 9216 B
    __syncthreads();
    if (g == 1) {
#pragma unroll
        for (int i = 0; i < 2; ++i)
#pragma unroll
            for (int j = 0; j < 4; ++j) comb[tl * 9 + i * 4 + j] = acc[i][j];
    }
    __syncthreads();
    if (g == 0) {
#pragma unroll
        for (int i = 0; i < 2; ++i)
#pragma unroll
            for (int j = 0; j < 4; ++j) acc[i][j] += comb[tl * 9 + i * 4 + j];
    }

    if (EPI == 0) {
        if (g == 0) {
            const int col = n0 + colL;
            float bias = b1[col];
            if (DUAL) bias += b2[col];
#pragma unroll
            for (int i = 0; i < 2; ++i) {
                const int mi = mh * 2 + i;
#pragma unroll
                for (int j = 0; j < 4; ++j) {
                    const int row = m0 + mi * 16 + q * 4 + j;
                    C[(size_t)row * ldc + col] = acc[i][j] + bias;
                }
            }
        }
        return;
    }

    // EPI == 2: LSTM pointwise. Gate cols interleaved (col' = unit*4+gate).
    float* G = (float*)(SM + 7680);   // byte 15360, 64x40 fp32 = 10240 B
    if (g == 0) {
        const int colG = n0 + colL;
        const int gate = colG & 3, unit = colG >> 2;
        const float bias = b1[gate * 1024 + unit] + b2[gate * 1024 + unit];
#pragma unroll
        for (int i = 0; i < 2; ++i) {
            const int mi = mh * 2 + i;
#pragma unroll
            for (int j = 0; j < 4; ++j)
                G[(mi * 16 + q * 4 + j) * 40 + colL] = acc[i][j] + bias;
        }
    }
    __syncthreads();
    {
        const int row = t >> 3, ul = t & 7;          // 64 rows x 8 units
        const float4 g4 = *(const float4*)&G[row * 40 + ul * 4];  // i,f,g,o
        const size_t ci = (size_t)(m0 + row) * HH + (n0 >> 2) + ul;
        const float cn = sigmoidf_(g4.y) * cvec[ci] + sigmoidf_(g4.x) * tanhf(g4.z);
        cvec[ci] = cn;
        hnew[ci] = sigmoidf_(g4.w) * tanhf(cn);
    }
}

// ---------------------------------------------------------------------------
// mgemm_pre: vis_att(bf16) = vis @ enc_att_w^T + b; optionally emits
// vis_bf = bf16(vis) as staging side-product. Tile 64x256.
// ---------------------------------------------------------------------------
template <int WRITE_VBF>
__global__ __launch_bounds__(256) void mgemm_pre(
    const float* __restrict__ A, const ushort* __restrict__ Wh, const ushort* __restrict__ Wl,
    const float* __restrict__ bias, ushort* __restrict__ C, ushort* __restrict__ vbf)
{
    __shared__ __align__(16) ushort Ah[64 * 40], Al[64 * 40];
    __shared__ __align__(16) ushort Bh[256 * 40], Bl[256 * 40];

    const int t = threadIdx.x;
    const int m0 = blockIdx.x * 64;
    const int w = t >> 6, lane = t & 63;
    const int l15 = lane & 15, q = lane >> 4;
    const int sr = t >> 2, sq = (t & 3) * 8;
    const int K = DV;

    f32x4 acc[4][4] = {};
    float4 pa0, pa1;
    auto prefA = [&](int k0) {
        const float* ap = &A[(size_t)(m0 + sr) * K + k0 + sq];
        pa0 = *(const float4*)ap;
        pa1 = *(const float4*)(ap + 4);
    };
    prefA(0);

    for (int c = 0; c < 32; ++c) {
        const int k0 = c << 5;
        __syncthreads();
        uint4 hq, lq; split8(pa0, pa1, hq, lq);
        *(uint4*)&Ah[sr * 40 + sq] = hq;
        *(uint4*)&Al[sr * 40 + sq] = lq;
        if (WRITE_VBF)
            *(uint4*)&vbf[(size_t)(m0 + sr) * K + k0 + sq] = hq;
#pragma unroll
        for (int i = 0; i < 4; ++i) {
            const int r = sr + 64 * i;
            *(uint4*)&Bh[r * 40 + sq] = *(const uint4*)&Wh[(size_t)r * K + k0 + sq];
            *(uint4*)&Bl[r * 40 + sq] = *(const uint4*)&Wl[(size_t)r * K + k0 + sq];
        }
        __syncthreads();
        if (c + 1 < 32) prefA((c + 1) << 5);

        bf16x8 ah[4], al[4];
#pragma unroll
        for (int mi = 0; mi < 4; ++mi) {
            ah[mi] = *(const bf16x8*)&Ah[(mi * 16 + l15) * 40 + q * 8];
            al[mi] = *(const bf16x8*)&Al[(mi * 16 + l15) * 40 + q * 8];
        }
#pragma unroll
        for (int ni = 0; ni < 4; ++ni) {
            const bf16x8 bh = *(const bf16x8*)&Bh[(w * 64 + ni * 16 + l15) * 40 + q * 8];
            const bf16x8 bl = *(const bf16x8*)&Bl[(w * 64 + ni * 16 + l15) * 40 + q * 8];
#pragma unroll
            for (int mi = 0; mi < 4; ++mi) {
                acc[mi][ni] = MFMA_B16(ah[mi], bh, acc[mi][ni]);
                acc[mi][ni] = MFMA_B16(ah[mi], bl, acc[mi][ni]);
                acc[mi][ni] = MFMA_B16(al[mi], bh, acc[mi][ni]);
            }
        }
    }

#pragma unroll
    for (int ni = 0; ni < 4; ++ni) {
        const int col = w * 64 + ni * 16 + l15;
        const float bb = bias[col];
#pragma unroll
        for (int mi = 0; mi < 4; ++mi)
#pragma unroll
            for (int j = 0; j < 4; ++j) {
                const int row = m0 + mi * 16 + q * 4 + j;
                C[(size_t)row * AT + col] = f2bf(acc[mi][ni][j] + bb);
            }
    }
}

// ---------------------------------------------------------------------------
// att_step: per batch row b (one 1024-thread block):
//   phase 0: dec[a] = h[b] . dec_att_w[a] + b_dec          (fp32, exact)
//   phase 1: logit[n] = sum_a tanh(vis_att+dec)*fw + fb
//   phase 2: softmax; phase 3: att_out = sc . vis (4-way region split)
// ---------------------------------------------------------------------------
template <int VBF>
__global__ __launch_bounds__(1024) void att_step(
    const ushort* __restrict__ vis_att, const float* __restrict__ h,
    const float* __restrict__ dec_w, const float* __restrict__ dec_b,
    const float* __restrict__ fw, const float* __restrict__ fbp,
    const void* __restrict__ visp, float* __restrict__ att_out)
{
    const int b = blockIdx.x;
    const int t = threadIdx.x;
    const int lane = t & 63;
    const int w = t >> 6;

    __shared__ float hs[HH];
    __shared__ float decs[AT];
    __shared__ float fwv[AT];
    __shared__ float logit[NR + 4];
    __shared__ float sc[NR + 4];
    __shared__ float red[8];
    __shared__ float part[4][DV];

    hs[t] = h[(size_t)b * HH + t];
    if (t < AT) fwv[t] = fw[t];
    __syncthreads();
    const float fb = fbp[0];

    // phase 0: dec — wave w computes outputs a = w*16 .. +15
#pragma unroll
    for (int j = 0; j < 16; ++j) {
        const int a = w * 16 + j;
        const float* wr = dec_w + (size_t)a * HH;
        float p = 0.f;
#pragma unroll
        for (int i = 0; i < 4; ++i) {
            const float4 wv = *(const float4*)&wr[i * 256 + lane * 4];
            const float4 hv = *(const float4*)&hs[i * 256 + lane * 4];
            p = fmaf(wv.x, hv.x, p); p = fmaf(wv.y, hv.y, p);
            p = fmaf(wv.z, hv.z, p); p = fmaf(wv.w, hv.w, p);
        }
        for (int off = 32; off; off >>= 1) p += __shfl_down(p, off);
        if (lane == 0) decs[a] = p + dec_b[a];
    }
    __syncthreads();

    // phase 1: logits — wave w handles rows n = w, w+16, ...
    for (int n = w; n < NR; n += 16) {
        const ushort4 v4 = *(const ushort4*)&vis_att[((size_t)b * NR + n) * AT + lane * 4];
        const int a = lane * 4;
        float s = tanhf(bf2f(v4.x) + decs[a]) * fwv[a];
        s = fmaf(tanhf(bf2f(v4.y) + decs[a + 1]), fwv[a + 1], s);
        s = fmaf(tanhf(bf2f(v4.z) + decs[a + 2]), fwv[a + 2], s);
        s = fmaf(tanhf(bf2f(v4.w) + decs[a + 3]), fwv[a + 3], s);
        for (int off = 32; off; off >>= 1) s += __shfl_down(s, off);
        if (lane == 0) logit[n] = s + fb;
    }
    __syncthreads();

    // phase 2: softmax (first 4 waves)
    float m = -1e30f, e = 0.f;
    if (t < NR) m = logit[t];
    if (t < 256) {
        for (int off = 32; off; off >>= 1) m = fmaxf(m, __shfl_down(m, off));
        if (lane == 0) red[w] = m;
    }
    __syncthreads();
    m = fmaxf(fmaxf(red[0], red[1]), fmaxf(red[2], red[3]));
    if (t < NR) e = expf(logit[t] - m);
    if (t < 256) {
        float ss = e;
        for (int off = 32; off; off >>= 1) ss += __shfl_down(ss, off);
        if (lane == 0) red[4 + w] = ss;
    }
    __syncthreads();
    const float S = red[4] + red[5] + red[6] + red[7];
    if (t < NR) sc[t] = e / S;
    __syncthreads();

    // phase 3: apply — 4-way region split (NR = 4*49), 256 thr x 4 cols each
    const int quarter = t >> 8;
    const int c4 = (t & 255) * 4;
    const int nbeg = quarter * (NR / 4), nend = nbeg + (NR / 4);
    float a0 = 0.f, a1 = 0.f, a2 = 0.f, a3 = 0.f;
    if (VBF) {
        const ushort* vb = (const ushort*)visp + (size_t)b * NR * DV + c4;
        for (int n = nbeg; n < nend; ++n) {
            const float s = sc[n];
            const ushort4 v = *(const ushort4*)&vb[(size_t)n * DV];
            a0 = fmaf(s, bf2f(v.x), a0);
            a1 = fmaf(s, bf2f(v.y), a1);
            a2 = fmaf(s, bf2f(v.z), a2);
            a3 = fmaf(s, bf2f(v.w), a3);
        }
    } else {
        const float* vb = (const float*)visp + (size_t)b * NR * DV + c4;
        for (int n = nbeg; n < nend; ++n) {
            const float s = sc[n];
            const float4 v = *(const float4*)&vb[(size_t)n * DV];
            a0 = fmaf(s, v.x, a0);
            a1 = fmaf(s, v.y, a1);
            a2 = fmaf(s, v.z, a2);
            a3 = fmaf(s, v.w, a3);
        }
    }
    float4 av; av.x = a0; av.y = a1; av.z = a2; av.w = a3;
    *(float4*)&part[quarter][c4] = av;
    __syncthreads();
    att_out[(size_t)b * DV + t] = part[0][t] + part[1][t] + part[2][t] + part[3][t];
}

// ---------------------------------------------------------------------------
// batched final stop projection over all (s,b): row = s*BB + b.
// ---------------------------------------------------------------------------
__global__ __launch_bounds__(256) void stop_final_all(
    const float* __restrict__ pt, const float* __restrict__ fw,
    const float* __restrict__ fb, float* __restrict__ outp)
{
    const int row = blockIdx.x;          // s*BB + b
    const int s = row >> 8, b = row & 255;
    const int t = threadIdx.x;
    const int lane = t & 63;
    const int w = t >> 6;

    __shared__ float red[16];
    const float v = pt[(size_t)row * IS + t];
    float p0 = v * fw[t];
    float p1 = v * fw[IS + t];
    for (int off = 32; off; off >>= 1) {
        p0 += __shfl_down(p0, off);
        p1 += __shfl_down(p1, off);
    }
    if (lane == 0) { red[w] = p0; red[8 + w] = p1; }
    __syncthreads();
    if (t == 0) {
        outp[((size_t)b * ST + s) * 2 + 0] = red[0] + red[1] + red[2] + red[3] + fb[0];
        outp[((size_t)b * ST + s) * 2 + 1] = red[8] + red[9] + red[10] + red[11] + fb[1];
    }
}

// ---------------------------------------------------------------------------
extern "C" void kernel_launch(void* const* d_in, const int* in_sizes, int n_in,
                              void* d_out, int out_size, void* d_ws, size_t ws_size,
                              hipStream_t stream)
{
    const float* vis        = (const float*)d_in[0];
    const float* enc_att_w  = (const float*)d_in[2];
    const float* enc_att_b  = (const float*)d_in[3];
    const float* dec_att_w  = (const float*)d_in[4];
    const float* dec_att_b  = (const float*)d_in[5];
    const float* full_att_w = (const float*)d_in[6];
    const float* full_att_b = (const float*)d_in[7];
    const float* ctx_w      = (const float*)d_in[8];
    const float* ctx_b      = (const float*)d_in[9];
    const float* W_ih       = (const float*)d_in[10];
    const float* b_ih       = (const float*)d_in[11];
    const float* W_hh       = (const float*)d_in[12];
    const float* b_hh       = (const float*)d_in[13];
    const float* topic_hid_w = (const float*)d_in[14];
    const float* topic_hid_b = (const float*)d_in[15];
    const float* topic_ctx_w = (const float*)d_in[16];
    const float* topic_ctx_b = (const float*)d_in[17];
    const float* stop_prev_w = (const float*)d_in[18];
    const float* stop_prev_b = (const float*)d_in[19];
    const float* stop_cur_w  = (const float*)d_in[20];
    const float* stop_cur_b  = (const float*)d_in[21];
    const float* final_stop_w = (const float*)d_in[22];
    const float* final_stop_b = (const float*)d_in[23];

    float* out_topics = (float*)d_out;                        // [B, ST, WI]
    float* out_ps     = (float*)d_out + (size_t)BB * ST * WI; // [B, ST, 2]

    char* ws = (char*)d_ws;
    size_t off = 0;
    auto alloc = [&](size_t bytes) -> void* {
        void* p = (void*)(ws + off);
        off += (bytes + 255) & ~(size_t)255;
        return p;
    };
    ushort* vis_att = (ushort*)alloc((size_t)BB * NR * AT * 2);      // 25.7 MB
    const size_t WTOT = 12582912;
    ushort* wh = (ushort*)alloc(WTOT * 2);                           // 25.2 MB
    ushort* wl = (ushort*)alloc(WTOT * 2);                           // 25.2 MB
    float* h_all   = (float*)alloc((size_t)(ST + 1) * BB * HH * 4);  // 11.5 MB
    float* ctx_all = (float*)alloc((size_t)ST * BB * SI * 4);        // 10.5 MB
    float* cbuf    = (float*)alloc((size_t)BB * HH * 4);
    float* att_out = (float*)alloc((size_t)BB * DV * 4);
    float* pt_all  = (float*)alloc((size_t)ST * BB * IS * 4);        // 2.6 MB
    if (off > ws_size) return;  // core workspace too small — fail visibly
    // optional bf16 copy of vis (98 MB) — falls back to fp32 reads if no room
    ushort* vis_bf = nullptr;
    {
        const size_t need = (size_t)BB * NR * DV * 2;
        if (off + need <= ws_size) vis_bf = (ushort*)alloc(need);
    }

    // weight segment offsets (elements) within the pool
    const size_t O_ENC = 0;          // 256x1024
    const size_t O_DEC = 262144;     // 256x1024 (dec is fused fp32 in att_step)
    const size_t O_CTX = 524288;     // 1024x1024
    const size_t O_IH  = 1572864;    // 4096x1024 (row-interleaved)
    const size_t O_HH  = 5767168;    // 4096x1024 (row-interleaved)
    const size_t O_TH  = 9961472;    // 1024x1024
    const size_t O_TC  = 11010048;   // 1024x1024
    const size_t O_SP  = 12058624;   // 256x1024
    const size_t O_SC  = 12320768;   // 256x1024

    CvtTab tab;
    const float* srcs[9] = {enc_att_w, dec_att_w, ctx_w, W_ih, W_hh,
                            topic_hid_w, topic_ctx_w, stop_prev_w, stop_cur_w};
    const size_t offs[9] = {O_ENC, O_DEC, O_CTX, O_IH, O_HH, O_TH, O_TC, O_SP, O_SC};
    for (int i = 0; i < 9; ++i) {
        tab.s[i] = srcs[i];
        tab.h[i] = wh + offs[i];
        tab.l[i] = wl + offs[i];
    }

    hipMemsetAsync(h_all, 0, (size_t)BB * HH * 4, stream);   // h_0 = 0
    hipMemsetAsync(cbuf, 0, (size_t)BB * HH * 4, stream);    // c_0 = 0

    convert_split<<<12288, 256, 0, stream>>>(tab);

    // hoisted encoder projection (+ bf16 vis side-product)
    if (vis_bf)
        mgemm_pre<1><<<(BB * NR) / 64, 256, 0, stream>>>(
            vis, wh + O_ENC, wl + O_ENC, enc_att_b, vis_att, vis_bf);
    else
        mgemm_pre<0><<<(BB * NR) / 64, 256, 0, stream>>>(
            vis, wh + O_ENC, wl + O_ENC, enc_att_b, vis_att, nullptr);

    for (int s = 0; s < ST; ++s) {
        float* hc = h_all + (size_t)s * BB * HH;
        float* hn = h_all + (size_t)(s + 1) * BB * HH;
        float* ctxs = ctx_all + (size_t)s * BB * SI;
        // fused dec + logits + softmax + apply
        if (vis_bf)
            att_step<1><<<BB, 1024, 0, stream>>>(vis_att, hc, dec_att_w, dec_att_b,
                                                 full_att_w, full_att_b, vis_bf, att_out);
        else
            att_step<0><<<BB, 1024, 0, stream>>>(vis_att, hc, dec_att_w, dec_att_b,
                                                 full_att_w, full_att_b, vis, att_out);
        // ctx = att_out @ ctx_w^T + ctx_b  (K-split across wave groups)
        mgemm8<0, 0><<<dim3(SI / 32, BB / 64), 512, 0, stream>>>(
            att_out, wh + O_CTX, wl + O_CTX, ctx_b,
            nullptr, nullptr, nullptr, nullptr,
            ctxs, DV, SI, nullptr, nullptr);
        // gates (interleaved) + fused LSTM pointwise (pass-split across groups)
        mgemm8<2, 1><<<dim3(4 * HH / 32, BB / 64), 512, 0, stream>>>(
            ctxs, wh + O_IH, wl + O_IH, b_ih,
            hc, wh + O_HH, wl + O_HH, b_hh,
            nullptr, SI, 0, cbuf, hn);
        (void)hn;
    }

    // deferred batched heads over all steps (rows = s*BB + b)
    mgemm<1, 1, 1><<<dim3(WI / 64, (ST * BB) / 64), 256, 0, stream>>>(
        h_all + (size_t)BB * HH, wh + O_TH, wl + O_TH, topic_hid_b,
        ctx_all, wh + O_TC, wl + O_TC, topic_ctx_b,
        out_topics, ST * BB, WI, HH, WI);
    mgemm<1, 1, 0><<<dim3(IS / 64, (ST * BB) / 64), 256, 0, stream>>>(
        h_all, wh + O_SP, wl + O_SP, stop_prev_b,
        h_all + (size_t)BB * HH, wh + O_SC, wl + O_SC, stop_cur_b,
        pt_all, ST * BB, IS, HH, IS);
    stop_final_all<<<ST * BB, 256, 0, stream>>>(pt_all, final_stop_w, final_stop_b, out_ps);
}